// Round 3
// baseline (847.694 us; speedup 1.0000x reference)
//
#include <hip/hip_runtime.h>

typedef float f32x4 __attribute__((ext_vector_type(4)));
typedef short bfrag __attribute__((ext_vector_type(8)));
typedef short sh4 __attribute__((ext_vector_type(4)));

__device__ __forceinline__ unsigned short f2bf(float x) {
  unsigned int u = __float_as_uint(x);
  return (unsigned short)((u + 0x7FFFu + ((u >> 16) & 1u)) >> 16);
}
__device__ __forceinline__ float bf2f(unsigned short u) {
  return __uint_as_float(((unsigned int)u) << 16);
}
__device__ __forceinline__ float wred_sum(float v) {
#pragma unroll
  for (int o = 32; o > 0; o >>= 1) v += __shfl_xor(v, o);
  return v;
}
__device__ __forceinline__ float wred_max(float v) {
#pragma unroll
  for (int o = 32; o > 0; o >>= 1) v = fmaxf(v, __shfl_xor(v, o));
  return v;
}

// ---------------------------------------------------------------------------
// Weight prep: Wt[n][k] (bf16, k-contiguous) = W[k][n].
// Only the 6 MFMA-consumed weights. fW/kW col-permuted as before.
// ---------------------------------------------------------------------------
struct Prep6 {
  const float* s[6];
  int K[6];
  int N[6];
  int base[6];
  int doff[6];
};

__global__ __launch_bounds__(256) void prep_w(Prep6 p, unsigned short* wt) {
  int t = blockIdx.x;
  int wi = 0;
#pragma unroll
  for (int i = 0; i < 5; ++i)
    if (t >= p.base[i + 1]) wi = i + 1;
  int lt = t - p.base[wi];
  int K = p.K[wi], N = p.N[wi];
  int tkn = (K + 31) >> 5;
  int tk = lt % tkn, tn = lt / tkn;
  __shared__ float tile[32][33];
  const float* src = p.s[wi];
#pragma unroll
  for (int i = 0; i < 4; ++i) {
    int flat = i * 256 + threadIdx.x;
    int kl = flat >> 5, nl = flat & 31;
    int k = tk * 32 + kl, n = tn * 32 + nl;
    tile[kl][nl] = (k < K && n < N) ? src[(size_t)k * N + n] : 0.f;
  }
  __syncthreads();
  unsigned short* dst = wt + p.doff[wi];
#pragma unroll
  for (int i = 0; i < 4; ++i) {
    int flat = i * 256 + threadIdx.x;
    int nl = flat >> 5, kl = flat & 31;
    int k = tk * 32 + kl, n = tn * 32 + nl;
    if (k < K && n < N) {
      int np = (wi < 2) ? ((n >= 3) ? n - 3 : n + 100) : n;
      dst[(size_t)np * K + k] = f2bf(tile[kl][nl]);
    }
  }
}

__global__ __launch_bounds__(256) void prep_bias(const float* __restrict__ fb_,
                                                 const float* __restrict__ kb_,
                                                 float* __restrict__ bf,
                                                 float* __restrict__ bk) {
  int t = threadIdx.x;
  if (t < 103) {
    int np = (t >= 3) ? t - 3 : t + 100;
    bf[np] = fb_[t];
    bk[np] = kb_[t];
  }
  if (t == 103) { bf[103] = 0.f; bk[103] = 0.f; }
}

// ---------------------------------------------------------------------------
// pack_bits: hard mask (mask>0) packed 1 bit/elem. 13,107,200 floats ->
// 409,600 uint32. Thread f: float4 -> 4 bits at ((f&7)*4); OR across 8-lane
// group via shfl_xor; lane (f&7)==0 stores the word.
// ---------------------------------------------------------------------------
__global__ __launch_bounds__(256) void pack_bits(const float* __restrict__ mask,
                                                 unsigned int* __restrict__ bits) {
  int tid = threadIdx.x;
  size_t f = (size_t)blockIdx.x * 256 + tid;
  float4 m = *(const float4*)(mask + f * 4);
  unsigned int n = (m.x > 0.f ? 1u : 0u) | (m.y > 0.f ? 2u : 0u) |
                   (m.z > 0.f ? 4u : 0u) | (m.w > 0.f ? 8u : 0u);
  n <<= ((tid & 7) * 4);
  n |= (unsigned int)__shfl_xor((int)n, 1);
  n |= (unsigned int)__shfl_xor((int)n, 2);
  n |= (unsigned int)__shfl_xor((int)n, 4);
  if ((tid & 7) == 0) bits[((size_t)blockIdx.x * 32) + (tid >> 3)] = n;
}

// ---------------------------------------------------------------------------
// MFMA GEMM: C[m][n] = act(sum_k A[m][k] * Wt[n][k] + bias[n]), row stride ldc
// ---------------------------------------------------------------------------
template <int ABF, int OBF>
__global__ __launch_bounds__(256) void gemm_mf(const void* Av,
                                               const unsigned short* __restrict__ Wt,
                                               const float* __restrict__ bias,
                                               void* Cv, int M, int K, int N, int ldc, int relu) {
  __shared__ short Al[64 * 72];
  __shared__ short Wl[64 * 72];
  int tid = threadIdx.x;
  int r0 = blockIdx.x * 64;
  int c0 = blockIdx.y * 64;
  int w = tid >> 6, lane = tid & 63, quad = lane >> 4, l15 = lane & 15;

  f32x4 acc[4];
#pragma unroll
  for (int mt = 0; mt < 4; ++mt) {
    acc[mt][0] = 0.f; acc[mt][1] = 0.f; acc[mt][2] = 0.f; acc[mt][3] = 0.f;
  }

  for (int k0 = 0; k0 < K; k0 += 64) {
    if (ABF) {
      const unsigned short* A = (const unsigned short*)Av;
#pragma unroll
      for (int p = 0; p < 2; ++p) {
        int flat = p * 256 + tid;
        int row = flat >> 3, k8 = flat & 7;
        bfrag v;
        if (r0 + row < M)
          v = *(const bfrag*)(A + (size_t)(r0 + row) * K + k0 + k8 * 8);
        else
          v = (bfrag)(short)0;
        *(bfrag*)(Al + row * 72 + k8 * 8) = v;
      }
    } else {
      const float* A = (const float*)Av;
#pragma unroll
      for (int p = 0; p < 4; ++p) {
        int flat = p * 256 + tid;
        int row = flat >> 4, c4 = flat & 15;
        sh4 o4;
        if (r0 + row < M) {
          float4 v = *(const float4*)(A + (size_t)(r0 + row) * K + k0 + c4 * 4);
          o4[0] = (short)f2bf(v.x); o4[1] = (short)f2bf(v.y);
          o4[2] = (short)f2bf(v.z); o4[3] = (short)f2bf(v.w);
        } else {
          o4[0] = 0; o4[1] = 0; o4[2] = 0; o4[3] = 0;
        }
        *(sh4*)(Al + row * 72 + c4 * 4) = o4;
      }
    }
#pragma unroll
    for (int p = 0; p < 2; ++p) {
      int flat = p * 256 + tid;
      int row = flat >> 3, k8 = flat & 7;
      bfrag v;
      if (c0 + row < N)
        v = *(const bfrag*)(Wt + (size_t)(c0 + row) * K + k0 + k8 * 8);
      else
        v = (bfrag)(short)0;
      *(bfrag*)(Wl + row * 72 + k8 * 8) = v;
    }
    __syncthreads();
#pragma unroll
    for (int kk = 0; kk < 2; ++kk) {
      bfrag bv = *(const bfrag*)(Wl + (w * 16 + l15) * 72 + kk * 32 + quad * 8);
#pragma unroll
      for (int mt = 0; mt < 4; ++mt) {
        bfrag av = *(const bfrag*)(Al + (mt * 16 + l15) * 72 + kk * 32 + quad * 8);
        acc[mt] = __builtin_amdgcn_mfma_f32_16x16x32_bf16(av, bv, acc[mt], 0, 0, 0);
      }
    }
    __syncthreads();
  }
  int col = c0 + w * 16 + l15;
  if (col < N) {
    float bv = bias ? bias[col] : 0.f;
#pragma unroll
    for (int mt = 0; mt < 4; ++mt)
#pragma unroll
      for (int r = 0; r < 4; ++r) {
        int m = r0 + mt * 16 + quad * 4 + r;
        if (m < M) {
          float v = acc[mt][r] + bv;
          if (relu) v = fmaxf(v, 0.f);
          if (OBF)
            ((unsigned short*)Cv)[(size_t)m * ldc + col] = f2bf(v);
          else
            ((float*)Cv)[(size_t)m * ldc + col] = v;
        }
      }
  }
}

// ---------------------------------------------------------------------------
// Phase A v4: v2 double-buffered pipeline, but A-tile comes from packed bits
// (1.6 MB instead of 52.4 MB of f32 mask). B staging (feat f32->bf16)
// unchanged. LDS 69,120 B -> 2 blocks/CU (grid 512 caps at 2/CU anyway).
// ---------------------------------------------------------------------------
__global__ __launch_bounds__(512, 4) void phaseA(const unsigned int* __restrict__ bits,
                                                 const float* __restrict__ feat,
                                                 float* __restrict__ partial) {
  int tid = threadIdx.x;
  int ks = blockIdx.x;  // 0..31
  int ct = blockIdx.y;  // 0..1
  int b  = blockIdx.z;  // 0..7
  __shared__ short Al[2][112 * 72];
  __shared__ short Bl[2][128 * 72];
  int w = tid >> 6, lane = tid & 63, quad = lane >> 4, l15 = lane & 15;

  // B staging geometry: 512 threads cover rows rbase+32p (p=0..3), 16 float4/row
  int rbase = tid >> 4;     // 0..31
  int c4 = tid & 15;        // float4 slot within the 64-float stage row
  const float* frow = feat + (size_t)(b * 256 + ct * 128 + rbase) * 16384 + c4 * 4;

  // A bits geometry: threads 0..399 -> (row, 16-col group q)
  int arow = tid >> 2, q = tid & 3;
  bool aact = tid < 400;
  const unsigned int* brow = bits + (size_t)(b * 100 + arow) * 512 + (q >> 1);

  f32x4 acc[7];
#pragma unroll
  for (int mt = 0; mt < 7; ++mt) {
    acc[mt][0] = 0.f; acc[mt][1] = 0.f; acc[mt][2] = 0.f; acc[mt][3] = 0.f;
  }

  // zero A pad rows 100..111 (both buffers) once
  for (int z = tid; z < 384; z += 512) {
    int bufi = z / 192, rem = z % 192;
    sh4 zz; zz[0] = 0; zz[1] = 0; zz[2] = 0; zz[3] = 0;
    *(sh4*)(&Al[bufi][(100 + (rem >> 4)) * 72 + (rem & 15) * 4]) = zz;
  }

  int k0 = ks * 512;
  // ---- prologue: stage 0 into buffer 0 ----
  {
    float4 bpf[4];
    unsigned int awd = 0;
#pragma unroll
    for (int p = 0; p < 4; ++p)
      bpf[p] = *(const float4*)(frow + (size_t)p * 32 * 16384 + k0);
    if (aact) awd = brow[k0 >> 5];
#pragma unroll
    for (int p = 0; p < 4; ++p) {
      int row = rbase + 32 * p;
      sh4 o4b;
      o4b[0] = (short)f2bf(bpf[p].x);
      o4b[1] = (short)f2bf(bpf[p].y);
      o4b[2] = (short)f2bf(bpf[p].z);
      o4b[3] = (short)f2bf(bpf[p].w);
      *(sh4*)(&Bl[0][row * 72 + c4 * 4]) = o4b;
    }
    if (aact) {
      unsigned int hw16 = (awd >> ((q & 1) * 16)) & 0xFFFFu;
      bfrag e0, e1;
#pragma unroll
      for (int i = 0; i < 8; ++i) e0[i] = ((hw16 >> i) & 1u) ? (short)0x3F80 : (short)0;
#pragma unroll
      for (int i = 0; i < 8; ++i) e1[i] = ((hw16 >> (i + 8)) & 1u) ? (short)0x3F80 : (short)0;
      *(bfrag*)(&Al[0][arow * 72 + q * 16]) = e0;
      *(bfrag*)(&Al[0][arow * 72 + q * 16 + 8]) = e1;
    }
  }
  __syncthreads();

  int cur = 0;
  for (int st = 0; st < 8; ++st) {
    // ---- issue prefetch for stage st+1 (consumed after the MFMAs) ----
    float4 bpf[4];
    unsigned int awd = 0;
    if (st < 7) {
      int kb = k0 + (st + 1) * 64;
#pragma unroll
      for (int p = 0; p < 4; ++p)
        bpf[p] = *(const float4*)(frow + (size_t)p * 32 * 16384 + kb);
      if (aact) awd = brow[kb >> 5];
    }
    // ---- compute stage st ----
#pragma unroll
    for (int kk = 0; kk < 2; ++kk) {
      bfrag bv = *(const bfrag*)(&Bl[cur][(w * 16 + l15) * 72 + kk * 32 + quad * 8]);
#pragma unroll
      for (int mt = 0; mt < 7; ++mt) {
        bfrag av = *(const bfrag*)(&Al[cur][(mt * 16 + l15) * 72 + kk * 32 + quad * 8]);
        acc[mt] = __builtin_amdgcn_mfma_f32_16x16x32_bf16(av, bv, acc[mt], 0, 0, 0);
      }
    }
    __builtin_amdgcn_sched_barrier(0);
    // ---- write stage st+1 into the other buffer ----
    if (st < 7) {
      int nxt = cur ^ 1;
#pragma unroll
      for (int p = 0; p < 4; ++p) {
        int row = rbase + 32 * p;
        sh4 o4b;
        o4b[0] = (short)f2bf(bpf[p].x);
        o4b[1] = (short)f2bf(bpf[p].y);
        o4b[2] = (short)f2bf(bpf[p].z);
        o4b[3] = (short)f2bf(bpf[p].w);
        *(sh4*)(&Bl[nxt][row * 72 + c4 * 4]) = o4b;
      }
      if (aact) {
        unsigned int hw16 = (awd >> ((q & 1) * 16)) & 0xFFFFu;
        bfrag e0, e1;
#pragma unroll
        for (int i = 0; i < 8; ++i) e0[i] = ((hw16 >> i) & 1u) ? (short)0x3F80 : (short)0;
#pragma unroll
        for (int i = 0; i < 8; ++i) e1[i] = ((hw16 >> (i + 8)) & 1u) ? (short)0x3F80 : (short)0;
        *(bfrag*)(&Al[nxt][arow * 72 + q * 16]) = e0;
        *(bfrag*)(&Al[nxt][arow * 72 + q * 16 + 8]) = e1;
      }
    }
    __syncthreads();
    cur ^= 1;
  }

  float* pb = partial + (size_t)(b * 32 + ks) * (100 * 256) + ct * 128 + w * 16 + l15;
#pragma unroll
  for (int mt = 0; mt < 7; ++mt)
#pragma unroll
    for (int r = 0; r < 4; ++r) {
      int m = mt * 16 + quad * 4 + r;
      if (m < 100) pb[(size_t)m * 256] = acc[mt][r];
    }
}

__global__ __launch_bounds__(256) void reduceA(const float* __restrict__ partial,
                                               float* __restrict__ fm) {
  int gid = blockIdx.x * 256 + threadIdx.x;
  int c = gid & 255, row = gid >> 8;
  int b = row / 100, n = row % 100;
  float s = 0.f;
#pragma unroll
  for (int ks = 0; ks < 32; ++ks)
    s += partial[((size_t)(b * 32 + ks) * 100 + n) * 256 + c];
  fm[(size_t)row * 256 + c] = s;
}

// ---------------------------------------------------------------------------
// dysep middle: wbuf rows (stride 104): [pw(100) | dw(3) | pad]
// ---------------------------------------------------------------------------
__global__ __launch_bounds__(256) void pointdw(const float* __restrict__ fm,
                                               const float* __restrict__ wbuf,
                                               float* __restrict__ point) {
  int tid = threadIdx.x;
  int b = blockIdx.y, c0 = blockIdx.x * 32;
  __shared__ float dl[100 * 33];
  for (int flat = tid; flat < 3200; flat += 256) {
    int n = flat >> 5, cl = flat & 31, c = c0 + cl;
    const float* fr = fm + (size_t)(b * 100 + n) * 256;
    const float* wr = wbuf + (size_t)(b * 100 + n) * 104;
    float x0 = (c > 0) ? fr[c - 1] : 0.f;
    float x1 = fr[c];
    float x2 = (c < 255) ? fr[c + 1] : 0.f;
    float d = wr[100] * x0 + wr[101] * x1 + wr[102] * x2;
    dl[n * 33 + cl] = fmaxf(d, 0.f);
  }
  __syncthreads();
  int cl = tid & 31, mg = tid >> 5;
  for (int m = mg; m < 100; m += 8) {
    const float4* pw4 = (const float4*)(wbuf + (size_t)(b * 100 + m) * 104);
    float a = 0.f;
#pragma unroll
    for (int n4 = 0; n4 < 25; ++n4) {
      float4 wv = pw4[n4];
      a += wv.x * dl[(n4 * 4 + 0) * 33 + cl] + wv.y * dl[(n4 * 4 + 1) * 33 + cl]
         + wv.z * dl[(n4 * 4 + 2) * 33 + cl] + wv.w * dl[(n4 * 4 + 3) * 33 + cl];
    }
    point[(size_t)(b * 100 + m) * 256 + c0 + cl] = a;
  }
}

// ---------------------------------------------------------------------------
__global__ __launch_bounds__(256) void ln2_kernel(const float* __restrict__ x,
                                                  const float* __restrict__ resid,
                                                  const float* __restrict__ g1, const float* __restrict__ b1,
                                                  const float* __restrict__ g2, const float* __restrict__ b2,
                                                  float* __restrict__ out) {
  int tid = threadIdx.x;
  int row = blockIdx.x * 4 + (tid >> 6);
  int lane = tid & 63;
  size_t base = (size_t)row * 256 + lane * 4;
  float4 v = *(const float4*)(x + base);
  float mean = wred_sum(v.x + v.y + v.z + v.w) * (1.f / 256.f);
  float d0 = v.x - mean, d1 = v.y - mean, d2 = v.z - mean, d3 = v.w - mean;
  float rs = rsqrtf(wred_sum(d0 * d0 + d1 * d1 + d2 * d2 + d3 * d3) * (1.f / 256.f) + 1e-5f);
  float4 gv = *(const float4*)(g1 + lane * 4);
  float4 bv = *(const float4*)(b1 + lane * 4);
  float4 rv = *(const float4*)(resid + base);
  float y0 = rv.x + d0 * rs * gv.x + bv.x;
  float y1 = rv.y + d1 * rs * gv.y + bv.y;
  float y2 = rv.z + d2 * rs * gv.z + bv.z;
  float y3 = rv.w + d3 * rs * gv.w + bv.w;
  float mean2 = wred_sum(y0 + y1 + y2 + y3) * (1.f / 256.f);
  float e0 = y0 - mean2, e1 = y1 - mean2, e2 = y2 - mean2, e3 = y3 - mean2;
  float rs2 = rsqrtf(wred_sum(e0 * e0 + e1 * e1 + e2 * e2 + e3 * e3) * (1.f / 256.f) + 1e-5f);
  float4 g2v = *(const float4*)(g2 + lane * 4);
  float4 b2v = *(const float4*)(b2 + lane * 4);
  float4 o;
  o.x = e0 * rs2 * g2v.x + b2v.x;
  o.y = e1 * rs2 * g2v.y + b2v.y;
  o.z = e2 * rs2 * g2v.z + b2v.z;
  o.w = e3 * rs2 * g2v.w + b2v.w;
  *(float4*)(out + base) = o;
}

__global__ __launch_bounds__(256) void ln_kernel(const float* __restrict__ x,
                                                 const float* __restrict__ res,
                                                 const float* __restrict__ g, const float* __restrict__ bb,
                                                 float* __restrict__ out, int relu,
                                                 float* __restrict__ copy2) {
  int tid = threadIdx.x;
  int row = blockIdx.x * 4 + (tid >> 6);
  int lane = tid & 63;
  size_t base = (size_t)row * 256 + lane * 4;
  float4 v = *(const float4*)(x + base);
  if (res) {
    float4 rv = *(const float4*)(res + base);
    v.x += rv.x; v.y += rv.y; v.z += rv.z; v.w += rv.w;
  }
  float mean = wred_sum(v.x + v.y + v.z + v.w) * (1.f / 256.f);
  float d0 = v.x - mean, d1 = v.y - mean, d2 = v.z - mean, d3 = v.w - mean;
  float rs = rsqrtf(wred_sum(d0 * d0 + d1 * d1 + d2 * d2 + d3 * d3) * (1.f / 256.f) + 1e-5f);
  float4 gv = *(const float4*)(g + lane * 4);
  float4 bv = *(const float4*)(bb + lane * 4);
  float4 o;
  o.x = d0 * rs * gv.x + bv.x;
  o.y = d1 * rs * gv.y + bv.y;
  o.z = d2 * rs * gv.z + bv.z;
  o.w = d3 * rs * gv.w + bv.w;
  if (relu) {
    o.x = fmaxf(o.x, 0.f); o.y = fmaxf(o.y, 0.f);
    o.z = fmaxf(o.z, 0.f); o.w = fmaxf(o.w, 0.f);
  }
  *(float4*)(out + base) = o;
  if (copy2) *(float4*)(copy2 + base) = o;
}

// ---------------------------------------------------------------------------
// MHA: one block per (head, batch). N=100, d=32.
// ---------------------------------------------------------------------------
__global__ __launch_bounds__(256) void attn_kernel(const float* __restrict__ qkv,
                                                   float* __restrict__ obuf) {
  int tid = threadIdx.x;
  int b = blockIdx.y, h = blockIdx.x;
  __shared__ float ktj[100 * 32];          // k [j][dd]
  __shared__ unsigned short vl[100 * 32];  // v bf16 [j][dd]
  __shared__ float sl[100 * 100];
  const float* base = qkv + (size_t)b * 100 * 768;
  for (int flat = tid; flat < 3200; flat += 256) {
    int j = flat >> 5, dd = flat & 31;
    ktj[j * 32 + dd] = base[(size_t)j * 768 + 256 + h * 32 + dd];
    vl[j * 32 + dd] = f2bf(base[(size_t)j * 768 + 512 + h * 32 + dd]);
  }
  __syncthreads();
  {
    int i = tid >> 1;
    int jh = (tid & 1) * 50;
    int qi = (i < 100) ? i : 0;
    const float4* q4 = (const float4*)(base + (size_t)qi * 768 + h * 32);
    float4 q[8];
#pragma unroll
    for (int d4 = 0; d4 < 8; ++d4) q[d4] = q4[d4];
    if (i < 100) {
      for (int jj = 0; jj < 50; ++jj) {
        int j = jh + jj;
        const float4* kr = (const float4*)(ktj + j * 32);
        float a = 0.f;
#pragma unroll
        for (int d4 = 0; d4 < 8; ++d4) {
          float4 kv = kr[d4];
          a += q[d4].x * kv.x + q[d4].y * kv.y + q[d4].z * kv.z + q[d4].w * kv.w;
        }
        sl[i * 100 + j] = a * 0.17677669529663687f;
      }
    }
  }
  __syncthreads();
  int w = tid >> 6, lane = tid & 63;
  for (int r = w; r < 100; r += 4) {
    float x0 = sl[r * 100 + lane];
    float x1 = (lane + 64 < 100) ? sl[r * 100 + lane + 64] : -1e30f;
    float mx = wred_max(fmaxf(x0, x1));
    float e0 = __expf(x0 - mx);
    float e1 = (lane + 64 < 100) ? __expf(x1 - mx) : 0.f;
    float inv = 1.f / wred_sum(e0 + e1);
    sl[r * 100 + lane] = e0 * inv;
    if (lane + 64 < 100) sl[r * 100 + lane + 64] = e1 * inv;
  }
  __syncthreads();
  for (int flat = tid; flat < 3200; flat += 256) {
    int i = flat >> 5, dd = flat & 31;
    float a = 0.f;
#pragma unroll 4
    for (int j = 0; j < 100; ++j) a += sl[i * 100 + j] * bf2f(vl[j * 32 + dd]);
    obuf[(size_t)(b * 100 + i) * 256 + h * 32 + dd] = a;
  }
}

// ---------------------------------------------------------------------------
// Fused cls + mask head: replaces 7 small GEMMs + 3 LNs (10 dispatches).
// 200 blocks x 4 waves; wave owns one row. fp32 VALU dots, weights streamed
// from L2 (coalesced 1KB/wave/k-step), LN via wave shuffle. Waves are
// independent (per-wave LDS rows); barriers only for safety-free wave-local
// LDS ordering which the compiler handles.
// ---------------------------------------------------------------------------
__global__ __launch_bounds__(256) void head_fused(
    const float* __restrict__ objb,
    const float* __restrict__ cls_w, const float* __restrict__ cls_g, const float* __restrict__ cls_b,
    const float* __restrict__ fcclsw, const float* __restrict__ fcclsb,
    const float* __restrict__ mask_w, const float* __restrict__ mask_g, const float* __restrict__ mask_b,
    const float* __restrict__ fcmw, const float* __restrict__ fcmb,
    float* __restrict__ out_cls, unsigned short* __restrict__ mk16) {
  int tid = threadIdx.x, wv = tid >> 6, lane = tid & 63;
  int row = blockIdx.x * 4 + wv;
  __shared__ float xs[4][260];
  __shared__ float x0[4][260];
  {
    float4 v = *(const float4*)(objb + (size_t)row * 256 + lane * 4);
    *(float4*)(&x0[wv][lane * 4]) = v;
    *(float4*)(&xs[wv][lane * 4]) = v;
  }
  // ---- mask chain: 3x (W @ x -> LN -> relu) ----
  for (int li = 0; li < 3; ++li) {
    const float* W = mask_w + li * 65536;
    float a0 = 0.f, a1 = 0.f, a2 = 0.f, a3 = 0.f;
#pragma unroll 4
    for (int k = 0; k < 256; ++k) {
      float xk = xs[wv][k];
      float4 wvv = *(const float4*)(W + (size_t)k * 256 + lane * 4);
      a0 += xk * wvv.x; a1 += xk * wvv.y; a2 += xk * wvv.z; a3 += xk * wvv.w;
    }
    float mean = wred_sum(a0 + a1 + a2 + a3) * (1.f / 256.f);
    float d0 = a0 - mean, d1 = a1 - mean, d2 = a2 - mean, d3 = a3 - mean;
    float rs = rsqrtf(wred_sum(d0 * d0 + d1 * d1 + d2 * d2 + d3 * d3) * (1.f / 256.f) + 1e-5f);
    float4 gv = *(const float4*)(mask_g + li * 256 + lane * 4);
    float4 bv = *(const float4*)(mask_b + li * 256 + lane * 4);
    float y0 = fmaxf(d0 * rs * gv.x + bv.x, 0.f);
    float y1 = fmaxf(d1 * rs * gv.y + bv.y, 0.f);
    float y2 = fmaxf(d2 * rs * gv.z + bv.z, 0.f);
    float y3 = fmaxf(d3 * rs * gv.w + bv.w, 0.f);
    float4 o; o.x = y0; o.y = y1; o.z = y2; o.w = y3;
    *(float4*)(&xs[wv][lane * 4]) = o;
  }
  // ---- fcm: mk = x @ fcmw + fcmb -> bf16 ----
  {
    float a0 = 0.f, a1 = 0.f, a2 = 0.f, a3 = 0.f;
#pragma unroll 4
    for (int k = 0; k < 256; ++k) {
      float xk = xs[wv][k];
      float4 wvv = *(const float4*)(fcmw + (size_t)k * 256 + lane * 4);
      a0 += xk * wvv.x; a1 += xk * wvv.y; a2 += xk * wvv.z; a3 += xk * wvv.w;
    }
    float4 bv = *(const float4*)(fcmb + lane * 4);
    sh4 o;
    o[0] = (short)f2bf(a0 + bv.x); o[1] = (short)f2bf(a1 + bv.y);
    o[2] = (short)f2bf(a2 + bv.z); o[3] = (short)f2bf(a3 + bv.w);
    *(sh4*)(mk16 + (size_t)row * 256 + lane * 4) = o;
  }
  // ---- cls chain: LN(relu(x0 @ cls_w)) -> fccls + bias ----
  {
    float a0 = 0.f, a1 = 0.f, a2 = 0.f, a3 = 0.f;
#pragma unroll 4
    for (int k = 0; k < 256; ++k) {
      float xk = x0[wv][k];
      float4 wvv = *(const float4*)(cls_w + (size_t)k * 256 + lane * 4);
      a0 += xk * wvv.x; a1 += xk * wvv.y; a2 += xk * wvv.z; a3 += xk * wvv.w;
    }
    float mean = wred_sum(a0 + a1 + a2 + a3) * (1.f / 256.f);
    float d0 = a0 - mean, d1 = a1 - mean, d2 = a2 - mean, d3 = a3 - mean;
    float rs = rsqrtf(wred_sum(d0 * d0 + d1 * d1 + d2 * d2 + d3 * d3) * (1.f / 256.f) + 1e-5f);
    float4 gv = *(const float4*)(cls_g + lane * 4);
    float4 bv = *(const float4*)(cls_b + lane * 4);
    float4 o;
    o.x = fmaxf(d0 * rs * gv.x + bv.x, 0.f);
    o.y = fmaxf(d1 * rs * gv.y + bv.y, 0.f);
    o.z = fmaxf(d2 * rs * gv.z + bv.z, 0.f);
    o.w = fmaxf(d3 * rs * gv.w + bv.w, 0.f);
    *(float4*)(&xs[wv][lane * 4]) = o;
    float c0 = 0.f, c1 = 0.f;
    for (int k = 0; k < 256; ++k) {
      float xk = xs[wv][k];
      c0 += xk * fcclsw[(size_t)k * 81 + lane];
      if (lane < 17) c1 += xk * fcclsw[(size_t)k * 81 + 64 + lane];
    }
    out_cls[(size_t)row * 81 + lane] = c0 + fcclsb[lane];
    if (lane < 17) out_cls[(size_t)row * 81 + 64 + lane] = c1 + fcclsb[64 + lane];
  }
}

// ---------------------------------------------------------------------------
// Phase E: out[b][q][hw] = sum_c mk[b][q][c] * feat[b][c][hw]
// LDS-free; A pre-converted bf16 (mk16), B converted in-flight.
// ---------------------------------------------------------------------------
__global__ __launch_bounds__(256, 4) void phaseE(const unsigned short* __restrict__ mk16,
                                                 const float* __restrict__ feat,
                                                 float* __restrict__ out) {
  int tid = threadIdx.x;
  int b = blockIdx.y;
  int hw0 = blockIdx.x * 128;
  int w = tid >> 6, lane = tid & 63, quad = lane >> 4, l15 = lane & 15;
  f32x4 acc[7][2];
#pragma unroll
  for (int mt = 0; mt < 7; ++mt)
#pragma unroll
    for (int nt = 0; nt < 2; ++nt) {
      acc[mt][nt][0] = 0.f; acc[mt][nt][1] = 0.f; acc[mt][nt][2] = 0.f; acc[mt][nt][3] = 0.f;
    }
  size_t fb = (size_t)b * 256 * 16384;
  int hwl = hw0 + w * 32 + l15;
  const unsigned short* mkb_b = mk16 + (size_t)b * 100 * 256;
  for (int kk = 0; kk < 8; ++kk) {
    bfrag bv[2];
#pragma unroll
    for (int nt = 0; nt < 2; ++nt) {
#pragma unroll
      for (int j = 0; j < 8; ++j) {
        float v = feat[fb + (size_t)(kk * 32 + quad * 8 + j) * 16384 + hwl + nt * 16];
        bv[nt][j] = (short)f2bf(v);
      }
    }
    bfrag av[7];
#pragma unroll
    for (int mt = 0; mt < 7; ++mt) {
      int row = mt * 16 + l15;
      int rr = (row < 100) ? row : 0;  // rows >=100 feed only unstored acc rows
      av[mt] = *(const bfrag*)(mkb_b + (size_t)rr * 256 + kk * 32 + quad * 8);
    }
#pragma unroll
    for (int mt = 0; mt < 7; ++mt) {
      acc[mt][0] = __builtin_amdgcn_mfma_f32_16x16x32_bf16(av[mt], bv[0], acc[mt][0], 0, 0, 0);
      acc[mt][1] = __builtin_amdgcn_mfma_f32_16x16x32_bf16(av[mt], bv[1], acc[mt][1], 0, 0, 0);
    }
  }
#pragma unroll
  for (int mt = 0; mt < 7; ++mt)
#pragma unroll
    for (int nt = 0; nt < 2; ++nt)
#pragma unroll
      for (int r = 0; r < 4; ++r) {
        int m = mt * 16 + quad * 4 + r;
        if (m < 100)
          out[(size_t)(b * 100 + m) * 16384 + hw0 + w * 32 + nt * 16 + l15] = acc[mt][nt][r];
      }
}

// ---------------------------------------------------------------------------
extern "C" void kernel_launch(void* const* d_in, const int* in_sizes, int n_in,
                              void* d_out, int out_size, void* d_ws, size_t ws_size,
                              hipStream_t stream) {
  const float* feat    = (const float*)d_in[0];
  const float* prop    = (const float*)d_in[1];
  const float* maskp   = (const float*)d_in[2];
  const float* fW      = (const float*)d_in[3];
  const float* fb_     = (const float*)d_in[4];
  const float* fng     = (const float*)d_in[5];
  const float* fnb     = (const float*)d_in[6];
  const float* f_ng    = (const float*)d_in[7];
  const float* f_nb    = (const float*)d_in[8];
  const float* kW      = (const float*)d_in[9];
  const float* kb_     = (const float*)d_in[10];
  const float* kng     = (const float*)d_in[11];
  const float* knb     = (const float*)d_in[12];
  const float* k_ng    = (const float*)d_in[13];
  const float* k_nb    = (const float*)d_in[14];
  const float* aw_in   = (const float*)d_in[15];
  const float* ab_in   = (const float*)d_in[16];
  const float* aw_out  = (const float*)d_in[17];
  const float* ab_out  = (const float*)d_in[18];
  const float* s_ng    = (const float*)d_in[19];
  const float* s_nb    = (const float*)d_in[20];
  const float* w1      = (const float*)d_in[21];
  const float* b1      = (const float*)d_in[22];
  const float* w2      = (const float*)d_in[23];
  const float* b2      = (const float*)d_in[24];
  const float* ffn_ng  = (const float*)d_in[25];
  const float* ffn_nb  = (const float*)d_in[26];
  const float* cls_w   = (const float*)d_in[27];
  const float* cls_g   = (const float*)d_in[28];
  const float* cls_b   = (const float*)d_in[29];
  const float* fcclsw  = (const float*)d_in[30];
  const float* fcclsb  = (const float*)d_in[31];
  const float* mask_w  = (const float*)d_in[32];
  const float* mask_g  = (const float*)d_in[33];
  const float* mask_b  = (const float*)d_in[34];
  const float* fcmw    = (const float*)d_in[35];
  const float* fcmb    = (const float*)d_in[36];
  float* out = (float*)d_out;

  // ---- workspace: 31.4 MB total (proven-safe bound is 33.03 MB) ----
  float* ws = (float*)d_ws;
  size_t off = 0;
  unsigned short* wt = (unsigned short*)(ws + off); off += 681984;  // 1,363,968 bf16
  float* fm     = ws + off; off += 204800;
  float* bias_f = ws + off; off += 104;
  float* bias_k = ws + off; off += 104;
  unsigned int* bitsbuf = (unsigned int*)(ws + off); off += 409600;  // 409,600 words
  float* partial = ws + off;   // union region: 8*32*100*256 = 6,553,600 floats
  float* ub = partial;
  size_t uo = 0;
  float* wb   = ub + uo; uo += 83200;   // 800 x 104
  float* pt   = ub + uo; uo += 204800;
  float* fbuf = ub + uo; uo += 204800;
  float* kkb  = ub + uo; uo += 204800;
  float* qkvb = ub + uo; uo += 614400;
  float* ob   = ub + uo; uo += 204800;
  float* mo   = ub + uo; uo += 204800;
  float* kk2  = ub + uo; uo += 204800;
  float* t1   = ub + uo; uo += 204800;
  float* objb = ub + uo; uo += 204800;
  float* mkb  = ub + uo; uo += 204800;
  unsigned short* ffn1b = (unsigned short*)(ub + uo); uo += 409600;  // 800x2048 bf16
  unsigned short* mkb16 = (unsigned short*)mkb;  // 800x256 bf16 view

  // Wt sub-offsets (shorts)
  const int wt_fW = 0, wt_kW = 26624, wt_ain = 53248, wt_aout = 249856;
  const int wt_w1 = 315392, wt_w2 = 839680;

  float* out_cls  = out;                       // [800][81]
  float* out_mask = out + 64800;               // [8][100][16384]
  float* out_obj  = out + 64800 + 13107200;    // [800][256]

  // ---- weight prep (transpose + bf16 + fW/kW col-permute) ----
  Prep6 p;
  const float* srcs[6] = {fW, kW, aw_in, aw_out, w1, w2};
  int Ks[6]    = {256, 256, 256, 256, 256, 2048};
  int Ns[6]    = {103, 103, 768, 256, 2048, 256};
  int doffs[6] = {wt_fW, wt_kW, wt_ain, wt_aout, wt_w1, wt_w2};
  int tb = 0;
  for (int i = 0; i < 6; ++i) {
    p.s[i] = srcs[i]; p.K[i] = Ks[i]; p.N[i] = Ns[i]; p.doff[i] = doffs[i];
    p.base[i] = tb;
    tb += ((Ks[i] + 31) / 32) * ((Ns[i] + 31) / 32);
  }
  prep_w<<<tb, 256, 0, stream>>>(p, wt);
  prep_bias<<<1, 256, 0, stream>>>(fb_, kb_, bias_f, bias_k);
  pack_bits<<<12800, 256, 0, stream>>>(maskp, bitsbuf);

  // f_masked = hard(mask) @ feat^T
  phaseA<<<dim3(32, 2, 8), 512, 0, stream>>>(bitsbuf, feat, partial);
  reduceA<<<800, 256, 0, stream>>>(partial, fm);
  // dysep 1  (partial region reused for activations from here)
  gemm_mf<0, 0><<<dim3(13, 2), 256, 0, stream>>>(prop, wt + wt_fW, bias_f, wb, 800, 256, 103, 104, 0);
  pointdw<<<dim3(8, 8), 256, 0, stream>>>(fm, wb, pt);
  ln2_kernel<<<200, 256, 0, stream>>>(pt, fm, fng, fnb, f_ng, f_nb, fbuf);
  // dysep 2
  gemm_mf<0, 0><<<dim3(13, 2), 256, 0, stream>>>(prop, wt + wt_kW, bias_k, wb, 800, 256, 103, 104, 0);
  pointdw<<<dim3(8, 8), 256, 0, stream>>>(fbuf, wb, pt);
  ln2_kernel<<<200, 256, 0, stream>>>(pt, fbuf, kng, knb, k_ng, k_nb, kkb);
  // MHA
  gemm_mf<0, 0><<<dim3(13, 12), 256, 0, stream>>>(kkb, wt + wt_ain, ab_in, qkvb, 800, 256, 768, 768, 0);
  attn_kernel<<<dim3(8, 8), 256, 0, stream>>>(qkvb, ob);
  gemm_mf<0, 0><<<dim3(13, 4), 256, 0, stream>>>(ob, wt + wt_aout, ab_out, mo, 800, 256, 256, 256, 0);
  ln_kernel<<<200, 256, 0, stream>>>(mo, kkb, s_ng, s_nb, kk2, 0, nullptr);
  // FFN
  gemm_mf<0, 1><<<dim3(13, 32), 256, 0, stream>>>(kk2, wt + wt_w1, b1, ffn1b, 800, 256, 2048, 2048, 1);
  gemm_mf<1, 0><<<dim3(13, 4), 256, 0, stream>>>(ffn1b, wt + wt_w2, b2, t1, 800, 2048, 256, 256, 0);
  ln_kernel<<<200, 256, 0, stream>>>(t1, kk2, ffn_ng, ffn_nb, objb, 0, out_obj);
  // fused cls + mask head (replaces 7 GEMMs + 3 LNs)
  head_fused<<<200, 256, 0, stream>>>(objb, cls_w, cls_g, cls_b, fcclsw, fcclsb,
                                      mask_w, mask_g, mask_b, fcmw, fcmb,
                                      out_cls, mkb16);
  // new_mask_preds = mk @ feat
  phaseE<<<dim3(128, 8), 256, 0, stream>>>(mkb16, feat, out_mask);
}

// Round 4
// 655.853 us; speedup vs baseline: 1.2925x; 1.2925x over previous
//
#include <hip/hip_runtime.h>

typedef float f32x4 __attribute__((ext_vector_type(4)));
typedef short bfrag __attribute__((ext_vector_type(8)));
typedef short sh4 __attribute__((ext_vector_type(4)));

__device__ __forceinline__ unsigned short f2bf(float x) {
  unsigned int u = __float_as_uint(x);
  return (unsigned short)((u + 0x7FFFu + ((u >> 16) & 1u)) >> 16);
}
__device__ __forceinline__ float bf2f(unsigned short u) {
  return __uint_as_float(((unsigned int)u) << 16);
}
__device__ __forceinline__ float wred_sum(float v) {
#pragma unroll
  for (int o = 32; o > 0; o >>= 1) v += __shfl_xor(v, o);
  return v;
}
__device__ __forceinline__ float wred_max(float v) {
#pragma unroll
  for (int o = 32; o > 0; o >>= 1) v = fmaxf(v, __shfl_xor(v, o));
  return v;
}

// ---------------------------------------------------------------------------
// Weight prep: Wt[n][k] (bf16, k-contiguous) = W[k][n].
// Only the 6 MFMA-consumed weights. fW/kW col-permuted as before.
// ---------------------------------------------------------------------------
struct Prep6 {
  const float* s[6];
  int K[6];
  int N[6];
  int base[6];
  int doff[6];
};

__global__ __launch_bounds__(256) void prep_w(Prep6 p, unsigned short* wt) {
  int t = blockIdx.x;
  int wi = 0;
#pragma unroll
  for (int i = 0; i < 5; ++i)
    if (t >= p.base[i + 1]) wi = i + 1;
  int lt = t - p.base[wi];
  int K = p.K[wi], N = p.N[wi];
  int tkn = (K + 31) >> 5;
  int tk = lt % tkn, tn = lt / tkn;
  __shared__ float tile[32][33];
  const float* src = p.s[wi];
#pragma unroll
  for (int i = 0; i < 4; ++i) {
    int flat = i * 256 + threadIdx.x;
    int kl = flat >> 5, nl = flat & 31;
    int k = tk * 32 + kl, n = tn * 32 + nl;
    tile[kl][nl] = (k < K && n < N) ? src[(size_t)k * N + n] : 0.f;
  }
  __syncthreads();
  unsigned short* dst = wt + p.doff[wi];
#pragma unroll
  for (int i = 0; i < 4; ++i) {
    int flat = i * 256 + threadIdx.x;
    int nl = flat >> 5, kl = flat & 31;
    int k = tk * 32 + kl, n = tn * 32 + nl;
    if (k < K && n < N) {
      int np = (wi < 2) ? ((n >= 3) ? n - 3 : n + 100) : n;
      dst[(size_t)np * K + k] = f2bf(tile[kl][nl]);
    }
  }
}

__global__ __launch_bounds__(256) void prep_bias(const float* __restrict__ fb_,
                                                 const float* __restrict__ kb_,
                                                 float* __restrict__ bf,
                                                 float* __restrict__ bk) {
  int t = threadIdx.x;
  if (t < 103) {
    int np = (t >= 3) ? t - 3 : t + 100;
    bf[np] = fb_[t];
    bk[np] = kb_[t];
  }
  if (t == 103) { bf[103] = 0.f; bk[103] = 0.f; }
}

// ---------------------------------------------------------------------------
// cast_w: head weights f32 -> bf16, original [k][n] layout (no transpose).
// ---------------------------------------------------------------------------
struct Cast4 {
  const float* s[4];
  int n[4];
  int base[4];
  int doff[4];
};

__global__ __launch_bounds__(256) void cast_w(Cast4 cc, unsigned short* dst) {
  int t = blockIdx.x;
  int wi = 0;
#pragma unroll
  for (int i = 0; i < 3; ++i)
    if (t >= cc.base[i + 1]) wi = i + 1;
  int lt = t - cc.base[wi];
  int idx = lt * 1024 + threadIdx.x * 4;
  if (idx + 3 < cc.n[wi]) {
    float4 v = *(const float4*)(cc.s[wi] + idx);
    sh4 o;
    o[0] = (short)f2bf(v.x); o[1] = (short)f2bf(v.y);
    o[2] = (short)f2bf(v.z); o[3] = (short)f2bf(v.w);
    *(sh4*)(dst + cc.doff[wi] + idx) = o;
  }
}

// ---------------------------------------------------------------------------
// pack_bits: hard mask (mask>0) packed 1 bit/elem.
// ---------------------------------------------------------------------------
__global__ __launch_bounds__(256) void pack_bits(const float* __restrict__ mask,
                                                 unsigned int* __restrict__ bits) {
  int tid = threadIdx.x;
  size_t f = (size_t)blockIdx.x * 256 + tid;
  float4 m = *(const float4*)(mask + f * 4);
  unsigned int n = (m.x > 0.f ? 1u : 0u) | (m.y > 0.f ? 2u : 0u) |
                   (m.z > 0.f ? 4u : 0u) | (m.w > 0.f ? 8u : 0u);
  n <<= ((tid & 7) * 4);
  n |= (unsigned int)__shfl_xor((int)n, 1);
  n |= (unsigned int)__shfl_xor((int)n, 2);
  n |= (unsigned int)__shfl_xor((int)n, 4);
  if ((tid & 7) == 0) bits[((size_t)blockIdx.x * 32) + (tid >> 3)] = n;
}

// ---------------------------------------------------------------------------
// MFMA GEMM: C[m][n] = act(sum_k A[m][k] * Wt[n][k] + bias[n]), row stride ldc
// ---------------------------------------------------------------------------
template <int ABF, int OBF>
__global__ __launch_bounds__(256) void gemm_mf(const void* Av,
                                               const unsigned short* __restrict__ Wt,
                                               const float* __restrict__ bias,
                                               void* Cv, int M, int K, int N, int ldc, int relu) {
  __shared__ short Al[64 * 72];
  __shared__ short Wl[64 * 72];
  int tid = threadIdx.x;
  int r0 = blockIdx.x * 64;
  int c0 = blockIdx.y * 64;
  int w = tid >> 6, lane = tid & 63, quad = lane >> 4, l15 = lane & 15;

  f32x4 acc[4];
#pragma unroll
  for (int mt = 0; mt < 4; ++mt) {
    acc[mt][0] = 0.f; acc[mt][1] = 0.f; acc[mt][2] = 0.f; acc[mt][3] = 0.f;
  }

  for (int k0 = 0; k0 < K; k0 += 64) {
    if (ABF) {
      const unsigned short* A = (const unsigned short*)Av;
#pragma unroll
      for (int p = 0; p < 2; ++p) {
        int flat = p * 256 + tid;
        int row = flat >> 3, k8 = flat & 7;
        bfrag v;
        if (r0 + row < M)
          v = *(const bfrag*)(A + (size_t)(r0 + row) * K + k0 + k8 * 8);
        else
          v = (bfrag)(short)0;
        *(bfrag*)(Al + row * 72 + k8 * 8) = v;
      }
    } else {
      const float* A = (const float*)Av;
#pragma unroll
      for (int p = 0; p < 4; ++p) {
        int flat = p * 256 + tid;
        int row = flat >> 4, c4 = flat & 15;
        sh4 o4;
        if (r0 + row < M) {
          float4 v = *(const float4*)(A + (size_t)(r0 + row) * K + k0 + c4 * 4);
          o4[0] = (short)f2bf(v.x); o4[1] = (short)f2bf(v.y);
          o4[2] = (short)f2bf(v.z); o4[3] = (short)f2bf(v.w);
        } else {
          o4[0] = 0; o4[1] = 0; o4[2] = 0; o4[3] = 0;
        }
        *(sh4*)(Al + row * 72 + c4 * 4) = o4;
      }
    }
#pragma unroll
    for (int p = 0; p < 2; ++p) {
      int flat = p * 256 + tid;
      int row = flat >> 3, k8 = flat & 7;
      bfrag v;
      if (c0 + row < N)
        v = *(const bfrag*)(Wt + (size_t)(c0 + row) * K + k0 + k8 * 8);
      else
        v = (bfrag)(short)0;
      *(bfrag*)(Wl + row * 72 + k8 * 8) = v;
    }
    __syncthreads();
#pragma unroll
    for (int kk = 0; kk < 2; ++kk) {
      bfrag bv = *(const bfrag*)(Wl + (w * 16 + l15) * 72 + kk * 32 + quad * 8);
#pragma unroll
      for (int mt = 0; mt < 4; ++mt) {
        bfrag av = *(const bfrag*)(Al + (mt * 16 + l15) * 72 + kk * 32 + quad * 8);
        acc[mt] = __builtin_amdgcn_mfma_f32_16x16x32_bf16(av, bv, acc[mt], 0, 0, 0);
      }
    }
    __syncthreads();
  }
  int col = c0 + w * 16 + l15;
  if (col < N) {
    float bv = bias ? bias[col] : 0.f;
#pragma unroll
    for (int mt = 0; mt < 4; ++mt)
#pragma unroll
      for (int r = 0; r < 4; ++r) {
        int m = r0 + mt * 16 + quad * 4 + r;
        if (m < M) {
          float v = acc[mt][r] + bv;
          if (relu) v = fmaxf(v, 0.f);
          if (OBF)
            ((unsigned short*)Cv)[(size_t)m * ldc + col] = f2bf(v);
          else
            ((float*)Cv)[(size_t)m * ldc + col] = v;
        }
      }
  }
}

// ---------------------------------------------------------------------------
// Phase A: partial[b][ks][m][c] += hard(mask)·feat; A-tile from packed bits.
// ---------------------------------------------------------------------------
__global__ __launch_bounds__(512, 4) void phaseA(const unsigned int* __restrict__ bits,
                                                 const float* __restrict__ feat,
                                                 float* __restrict__ partial) {
  int tid = threadIdx.x;
  int ks = blockIdx.x;  // 0..31
  int ct = blockIdx.y;  // 0..1
  int b  = blockIdx.z;  // 0..7
  __shared__ short Al[2][112 * 72];
  __shared__ short Bl[2][128 * 72];
  int w = tid >> 6, lane = tid & 63, quad = lane >> 4, l15 = lane & 15;

  int rbase = tid >> 4;
  int c4 = tid & 15;
  const float* frow = feat + (size_t)(b * 256 + ct * 128 + rbase) * 16384 + c4 * 4;

  int arow = tid >> 2, q = tid & 3;
  bool aact = tid < 400;
  const unsigned int* brow = bits + (size_t)(b * 100 + arow) * 512 + (q >> 1);

  f32x4 acc[7];
#pragma unroll
  for (int mt = 0; mt < 7; ++mt) {
    acc[mt][0] = 0.f; acc[mt][1] = 0.f; acc[mt][2] = 0.f; acc[mt][3] = 0.f;
  }

  for (int z = tid; z < 384; z += 512) {
    int bufi = z / 192, rem = z % 192;
    sh4 zz; zz[0] = 0; zz[1] = 0; zz[2] = 0; zz[3] = 0;
    *(sh4*)(&Al[bufi][(100 + (rem >> 4)) * 72 + (rem & 15) * 4]) = zz;
  }

  int k0 = ks * 512;
  {
    float4 bpf[4];
    unsigned int awd = 0;
#pragma unroll
    for (int p = 0; p < 4; ++p)
      bpf[p] = *(const float4*)(frow + (size_t)p * 32 * 16384 + k0);
    if (aact) awd = brow[k0 >> 5];
#pragma unroll
    for (int p = 0; p < 4; ++p) {
      int row = rbase + 32 * p;
      sh4 o4b;
      o4b[0] = (short)f2bf(bpf[p].x);
      o4b[1] = (short)f2bf(bpf[p].y);
      o4b[2] = (short)f2bf(bpf[p].z);
      o4b[3] = (short)f2bf(bpf[p].w);
      *(sh4*)(&Bl[0][row * 72 + c4 * 4]) = o4b;
    }
    if (aact) {
      unsigned int hw16 = (awd >> ((q & 1) * 16)) & 0xFFFFu;
      bfrag e0, e1;
#pragma unroll
      for (int i = 0; i < 8; ++i) e0[i] = ((hw16 >> i) & 1u) ? (short)0x3F80 : (short)0;
#pragma unroll
      for (int i = 0; i < 8; ++i) e1[i] = ((hw16 >> (i + 8)) & 1u) ? (short)0x3F80 : (short)0;
      *(bfrag*)(&Al[0][arow * 72 + q * 16]) = e0;
      *(bfrag*)(&Al[0][arow * 72 + q * 16 + 8]) = e1;
    }
  }
  __syncthreads();

  int cur = 0;
  for (int st = 0; st < 8; ++st) {
    float4 bpf[4];
    unsigned int awd = 0;
    if (st < 7) {
      int kb = k0 + (st + 1) * 64;
#pragma unroll
      for (int p = 0; p < 4; ++p)
        bpf[p] = *(const float4*)(frow + (size_t)p * 32 * 16384 + kb);
      if (aact) awd = brow[kb >> 5];
    }
#pragma unroll
    for (int kk = 0; kk < 2; ++kk) {
      bfrag bv = *(const bfrag*)(&Bl[cur][(w * 16 + l15) * 72 + kk * 32 + quad * 8]);
#pragma unroll
      for (int mt = 0; mt < 7; ++mt) {
        bfrag av = *(const bfrag*)(&Al[cur][(mt * 16 + l15) * 72 + kk * 32 + quad * 8]);
        acc[mt] = __builtin_amdgcn_mfma_f32_16x16x32_bf16(av, bv, acc[mt], 0, 0, 0);
      }
    }
    __builtin_amdgcn_sched_barrier(0);
    if (st < 7) {
      int nxt = cur ^ 1;
#pragma unroll
      for (int p = 0; p < 4; ++p) {
        int row = rbase + 32 * p;
        sh4 o4b;
        o4b[0] = (short)f2bf(bpf[p].x);
        o4b[1] = (short)f2bf(bpf[p].y);
        o4b[2] = (short)f2bf(bpf[p].z);
        o4b[3] = (short)f2bf(bpf[p].w);
        *(sh4*)(&Bl[nxt][row * 72 + c4 * 4]) = o4b;
      }
      if (aact) {
        unsigned int hw16 = (awd >> ((q & 1) * 16)) & 0xFFFFu;
        bfrag e0, e1;
#pragma unroll
        for (int i = 0; i < 8; ++i) e0[i] = ((hw16 >> i) & 1u) ? (short)0x3F80 : (short)0;
#pragma unroll
        for (int i = 0; i < 8; ++i) e1[i] = ((hw16 >> (i + 8)) & 1u) ? (short)0x3F80 : (short)0;
        *(bfrag*)(&Al[nxt][arow * 72 + q * 16]) = e0;
        *(bfrag*)(&Al[nxt][arow * 72 + q * 16 + 8]) = e1;
      }
    }
    __syncthreads();
    cur ^= 1;
  }

  float* pb = partial + (size_t)(b * 32 + ks) * (100 * 256) + ct * 128 + w * 16 + l15;
#pragma unroll
  for (int mt = 0; mt < 7; ++mt)
#pragma unroll
    for (int r = 0; r < 4; ++r) {
      int m = mt * 16 + quad * 4 + r;
      if (m < 100) pb[(size_t)m * 256] = acc[mt][r];
    }
}

__global__ __launch_bounds__(256) void reduceA(const float* __restrict__ partial,
                                               float* __restrict__ fm) {
  int gid = blockIdx.x * 256 + threadIdx.x;
  int c = gid & 255, row = gid >> 8;
  int b = row / 100, n = row % 100;
  float s = 0.f;
#pragma unroll
  for (int ks = 0; ks < 32; ++ks)
    s += partial[((size_t)(b * 32 + ks) * 100 + n) * 256 + c];
  fm[(size_t)row * 256 + c] = s;
}

// ---------------------------------------------------------------------------
// dysep middle: wbuf rows (stride 104): [pw(100) | dw(3) | pad]
// ---------------------------------------------------------------------------
__global__ __launch_bounds__(256) void pointdw(const float* __restrict__ fm,
                                               const float* __restrict__ wbuf,
                                               float* __restrict__ point) {
  int tid = threadIdx.x;
  int b = blockIdx.y, c0 = blockIdx.x * 32;
  __shared__ float dl[100 * 33];
  for (int flat = tid; flat < 3200; flat += 256) {
    int n = flat >> 5, cl = flat & 31, c = c0 + cl;
    const float* fr = fm + (size_t)(b * 100 + n) * 256;
    const float* wr = wbuf + (size_t)(b * 100 + n) * 104;
    float x0 = (c > 0) ? fr[c - 1] : 0.f;
    float x1 = fr[c];
    float x2 = (c < 255) ? fr[c + 1] : 0.f;
    float d = wr[100] * x0 + wr[101] * x1 + wr[102] * x2;
    dl[n * 33 + cl] = fmaxf(d, 0.f);
  }
  __syncthreads();
  int cl = tid & 31, mg = tid >> 5;
  for (int m = mg; m < 100; m += 8) {
    const float4* pw4 = (const float4*)(wbuf + (size_t)(b * 100 + m) * 104);
    float a = 0.f;
#pragma unroll
    for (int n4 = 0; n4 < 25; ++n4) {
      float4 wv = pw4[n4];
      a += wv.x * dl[(n4 * 4 + 0) * 33 + cl] + wv.y * dl[(n4 * 4 + 1) * 33 + cl]
         + wv.z * dl[(n4 * 4 + 2) * 33 + cl] + wv.w * dl[(n4 * 4 + 3) * 33 + cl];
    }
    point[(size_t)(b * 100 + m) * 256 + c0 + cl] = a;
  }
}

// ---------------------------------------------------------------------------
__global__ __launch_bounds__(256) void ln2_kernel(const float* __restrict__ x,
                                                  const float* __restrict__ resid,
                                                  const float* __restrict__ g1, const float* __restrict__ b1,
                                                  const float* __restrict__ g2, const float* __restrict__ b2,
                                                  float* __restrict__ out) {
  int tid = threadIdx.x;
  int row = blockIdx.x * 4 + (tid >> 6);
  int lane = tid & 63;
  size_t base = (size_t)row * 256 + lane * 4;
  float4 v = *(const float4*)(x + base);
  float mean = wred_sum(v.x + v.y + v.z + v.w) * (1.f / 256.f);
  float d0 = v.x - mean, d1 = v.y - mean, d2 = v.z - mean, d3 = v.w - mean;
  float rs = rsqrtf(wred_sum(d0 * d0 + d1 * d1 + d2 * d2 + d3 * d3) * (1.f / 256.f) + 1e-5f);
  float4 gv = *(const float4*)(g1 + lane * 4);
  float4 bv = *(const float4*)(b1 + lane * 4);
  float4 rv = *(const float4*)(resid + base);
  float y0 = rv.x + d0 * rs * gv.x + bv.x;
  float y1 = rv.y + d1 * rs * gv.y + bv.y;
  float y2 = rv.z + d2 * rs * gv.z + bv.z;
  float y3 = rv.w + d3 * rs * gv.w + bv.w;
  float mean2 = wred_sum(y0 + y1 + y2 + y3) * (1.f / 256.f);
  float e0 = y0 - mean2, e1 = y1 - mean2, e2 = y2 - mean2, e3 = y3 - mean2;
  float rs2 = rsqrtf(wred_sum(e0 * e0 + e1 * e1 + e2 * e2 + e3 * e3) * (1.f / 256.f) + 1e-5f);
  float4 g2v = *(const float4*)(g2 + lane * 4);
  float4 b2v = *(const float4*)(b2 + lane * 4);
  float4 o;
  o.x = e0 * rs2 * g2v.x + b2v.x;
  o.y = e1 * rs2 * g2v.y + b2v.y;
  o.z = e2 * rs2 * g2v.z + b2v.z;
  o.w = e3 * rs2 * g2v.w + b2v.w;
  *(float4*)(out + base) = o;
}

__global__ __launch_bounds__(256) void ln_kernel(const float* __restrict__ x,
                                                 const float* __restrict__ res,
                                                 const float* __restrict__ g, const float* __restrict__ bb,
                                                 float* __restrict__ out, int relu,
                                                 float* __restrict__ copy2) {
  int tid = threadIdx.x;
  int row = blockIdx.x * 4 + (tid >> 6);
  int lane = tid & 63;
  size_t base = (size_t)row * 256 + lane * 4;
  float4 v = *(const float4*)(x + base);
  if (res) {
    float4 rv = *(const float4*)(res + base);
    v.x += rv.x; v.y += rv.y; v.z += rv.z; v.w += rv.w;
  }
  float mean = wred_sum(v.x + v.y + v.z + v.w) * (1.f / 256.f);
  float d0 = v.x - mean, d1 = v.y - mean, d2 = v.z - mean, d3 = v.w - mean;
  float rs = rsqrtf(wred_sum(d0 * d0 + d1 * d1 + d2 * d2 + d3 * d3) * (1.f / 256.f) + 1e-5f);
  float4 gv = *(const float4*)(g + lane * 4);
  float4 bv = *(const float4*)(bb + lane * 4);
  float4 o;
  o.x = d0 * rs * gv.x + bv.x;
  o.y = d1 * rs * gv.y + bv.y;
  o.z = d2 * rs * gv.z + bv.z;
  o.w = d3 * rs * gv.w + bv.w;
  if (relu) {
    o.x = fmaxf(o.x, 0.f); o.y = fmaxf(o.y, 0.f);
    o.z = fmaxf(o.z, 0.f); o.w = fmaxf(o.w, 0.f);
  }
  *(float4*)(out + base) = o;
  if (copy2) *(float4*)(copy2 + base) = o;
}

// ---------------------------------------------------------------------------
// MHA: one block per (head, batch). N=100, d=32.
// ---------------------------------------------------------------------------
__global__ __launch_bounds__(256) void attn_kernel(const float* __restrict__ qkv,
                                                   float* __restrict__ obuf) {
  int tid = threadIdx.x;
  int b = blockIdx.y, h = blockIdx.x;
  __shared__ float ktj[100 * 32];          // k [j][dd]
  __shared__ unsigned short vl[100 * 32];  // v bf16 [j][dd]
  __shared__ float sl[100 * 100];
  const float* base = qkv + (size_t)b * 100 * 768;
  for (int flat = tid; flat < 3200; flat += 256) {
    int j = flat >> 5, dd = flat & 31;
    ktj[j * 32 + dd] = base[(size_t)j * 768 + 256 + h * 32 + dd];
    vl[j * 32 + dd] = f2bf(base[(size_t)j * 768 + 512 + h * 32 + dd]);
  }
  __syncthreads();
  {
    int i = tid >> 1;
    int jh = (tid & 1) * 50;
    int qi = (i < 100) ? i : 0;
    const float4* q4 = (const float4*)(base + (size_t)qi * 768 + h * 32);
    float4 q[8];
#pragma unroll
    for (int d4 = 0; d4 < 8; ++d4) q[d4] = q4[d4];
    if (i < 100) {
      for (int jj = 0; jj < 50; ++jj) {
        int j = jh + jj;
        const float4* kr = (const float4*)(ktj + j * 32);
        float a = 0.f;
#pragma unroll
        for (int d4 = 0; d4 < 8; ++d4) {
          float4 kv = kr[d4];
          a += q[d4].x * kv.x + q[d4].y * kv.y + q[d4].z * kv.z + q[d4].w * kv.w;
        }
        sl[i * 100 + j] = a * 0.17677669529663687f;
      }
    }
  }
  __syncthreads();
  int w = tid >> 6, lane = tid & 63;
  for (int r = w; r < 100; r += 4) {
    float x0 = sl[r * 100 + lane];
    float x1 = (lane + 64 < 100) ? sl[r * 100 + lane + 64] : -1e30f;
    float mx = wred_max(fmaxf(x0, x1));
    float e0 = __expf(x0 - mx);
    float e1 = (lane + 64 < 100) ? __expf(x1 - mx) : 0.f;
    float inv = 1.f / wred_sum(e0 + e1);
    sl[r * 100 + lane] = e0 * inv;
    if (lane + 64 < 100) sl[r * 100 + lane + 64] = e1 * inv;
  }
  __syncthreads();
  for (int flat = tid; flat < 3200; flat += 256) {
    int i = flat >> 5, dd = flat & 31;
    float a = 0.f;
#pragma unroll 4
    for (int j = 0; j < 100; ++j) a += sl[i * 100 + j] * bf2f(vl[j * 32 + dd]);
    obuf[(size_t)(b * 100 + i) * 256 + h * 32 + dd] = a;
  }
}

// ---------------------------------------------------------------------------
// Fused cls + mask head v2: one ROW per block (800 blocks, 4 waves).
// K=256 dot split across 4 waves (64 serial steps each), partials summed via
// LDS, LN computed redundantly per-wave via shuffle. Weights bf16 (whd).
// ---------------------------------------------------------------------------
__global__ __launch_bounds__(256) void head_fused(
    const float* __restrict__ objb,
    const unsigned short* __restrict__ whd,
    const float* __restrict__ cls_g, const float* __restrict__ cls_b,
    const float* __restrict__ fcclsb,
    const float* __restrict__ mask_g, const float* __restrict__ mask_b,
    const float* __restrict__ fcmb,
    float* __restrict__ out_cls, unsigned short* __restrict__ mk16) {
  const int WH_CLS = 0, WH_FCCLS = 65536, WH_M = 86272, WH_FCM = 282880;
  int tid = threadIdx.x, wv = tid >> 6, lane = tid & 63;
  int row = blockIdx.x;
  __shared__ float xs[256];
  __shared__ float x0s[256];
  __shared__ float ps[4][256];
  if (wv == 0) {
    float4 v = *(const float4*)(objb + (size_t)row * 256 + lane * 4);
    *(float4*)(&xs[lane * 4]) = v;
    *(float4*)(&x0s[lane * 4]) = v;
  }
  __syncthreads();
  int c = lane * 4;
  int kb = wv * 64;

  // ---- mask chain: 3x (x @ W -> LN -> relu) ----
  for (int li = 0; li < 3; ++li) {
    const unsigned short* W = whd + WH_M + li * 65536;
    float a0 = 0.f, a1 = 0.f, a2 = 0.f, a3 = 0.f;
#pragma unroll 8
    for (int k = kb; k < kb + 64; ++k) {
      float xk = xs[k];
      sh4 w4 = *(const sh4*)(W + (size_t)k * 256 + c);
      a0 += xk * bf2f((unsigned short)w4[0]);
      a1 += xk * bf2f((unsigned short)w4[1]);
      a2 += xk * bf2f((unsigned short)w4[2]);
      a3 += xk * bf2f((unsigned short)w4[3]);
    }
    ps[wv][c] = a0; ps[wv][c + 1] = a1; ps[wv][c + 2] = a2; ps[wv][c + 3] = a3;
    __syncthreads();
    float s0 = ps[0][c] + ps[1][c] + ps[2][c] + ps[3][c];
    float s1 = ps[0][c + 1] + ps[1][c + 1] + ps[2][c + 1] + ps[3][c + 1];
    float s2 = ps[0][c + 2] + ps[1][c + 2] + ps[2][c + 2] + ps[3][c + 2];
    float s3 = ps[0][c + 3] + ps[1][c + 3] + ps[2][c + 3] + ps[3][c + 3];
    float mean = wred_sum(s0 + s1 + s2 + s3) * (1.f / 256.f);
    float d0 = s0 - mean, d1 = s1 - mean, d2 = s2 - mean, d3 = s3 - mean;
    float rs = rsqrtf(wred_sum(d0 * d0 + d1 * d1 + d2 * d2 + d3 * d3) * (1.f / 256.f) + 1e-5f);
    float4 gv = *(const float4*)(mask_g + li * 256 + c);
    float4 bv = *(const float4*)(mask_b + li * 256 + c);
    float4 o;
    o.x = fmaxf(d0 * rs * gv.x + bv.x, 0.f);
    o.y = fmaxf(d1 * rs * gv.y + bv.y, 0.f);
    o.z = fmaxf(d2 * rs * gv.z + bv.z, 0.f);
    o.w = fmaxf(d3 * rs * gv.w + bv.w, 0.f);
    __syncthreads();  // all ps reads done before ps reused; xs reads done in k-loop
    *(float4*)(&xs[c]) = o;  // identical values from all waves
    __syncthreads();
  }
  // ---- fcm: mk16 = bf16(x @ Wfcm + b) ----
  {
    const unsigned short* W = whd + WH_FCM;
    float a0 = 0.f, a1 = 0.f, a2 = 0.f, a3 = 0.f;
#pragma unroll 8
    for (int k = kb; k < kb + 64; ++k) {
      float xk = xs[k];
      sh4 w4 = *(const sh4*)(W + (size_t)k * 256 + c);
      a0 += xk * bf2f((unsigned short)w4[0]);
      a1 += xk * bf2f((unsigned short)w4[1]);
      a2 += xk * bf2f((unsigned short)w4[2]);
      a3 += xk * bf2f((unsigned short)w4[3]);
    }
    ps[wv][c] = a0; ps[wv][c + 1] = a1; ps[wv][c + 2] = a2; ps[wv][c + 3] = a3;
    __syncthreads();
    if (wv == 0) {
      float s0 = ps[0][c] + ps[1][c] + ps[2][c] + ps[3][c];
      float s1 = ps[0][c + 1] + ps[1][c + 1] + ps[2][c + 1] + ps[3][c + 1];
      float s2 = ps[0][c + 2] + ps[1][c + 2] + ps[2][c + 2] + ps[3][c + 2];
      float s3 = ps[0][c + 3] + ps[1][c + 3] + ps[2][c + 3] + ps[3][c + 3];
      float4 bv = *(const float4*)(fcmb + c);
      sh4 o;
      o[0] = (short)f2bf(s0 + bv.x); o[1] = (short)f2bf(s1 + bv.y);
      o[2] = (short)f2bf(s2 + bv.z); o[3] = (short)f2bf(s3 + bv.w);
      *(sh4*)(mk16 + (size_t)row * 256 + c) = o;
    }
    __syncthreads();
  }
  // ---- cls: LN(relu? no: relu(LN(x0 @ cls_w))) -> xs ----
  {
    const unsigned short* W = whd + WH_CLS;
    float a0 = 0.f, a1 = 0.f, a2 = 0.f, a3 = 0.f;
#pragma unroll 8
    for (int k = kb; k < kb + 64; ++k) {
      float xk = x0s[k];
      sh4 w4 = *(const sh4*)(W + (size_t)k * 256 + c);
      a0 += xk * bf2f((unsigned short)w4[0]);
      a1 += xk * bf2f((unsigned short)w4[1]);
      a2 += xk * bf2f((unsigned short)w4[2]);
      a3 += xk * bf2f((unsigned short)w4[3]);
    }
    ps[wv][c] = a0; ps[wv][c + 1] = a1; ps[wv][c + 2] = a2; ps[wv][c + 3] = a3;
    __syncthreads();
    float s0 = ps[0][c] + ps[1][c] + ps[2][c] + ps[3][c];
    float s1 = ps[0][c + 1] + ps[1][c + 1] + ps[2][c + 1] + ps[3][c + 1];
    float s2 = ps[0][c + 2] + ps[1][c + 2] + ps[2][c + 2] + ps[3][c + 2];
    float s3 = ps[0][c + 3] + ps[1][c + 3] + ps[2][c + 3] + ps[3][c + 3];
    float mean = wred_sum(s0 + s1 + s2 + s3) * (1.f / 256.f);
    float d0 = s0 - mean, d1 = s1 - mean, d2 = s2 - mean, d3 = s3 - mean;
    float rs = rsqrtf(wred_sum(d0 * d0 + d1 * d1 + d2 * d2 + d3 * d3) * (1.f / 256.f) + 1e-5f);
    float4 gv = *(const float4*)(cls_g + c);
    float4 bv = *(const float4*)(cls_b + c);
    float4 o;
    o.x = fmaxf(d0 * rs * gv.x + bv.x, 0.f);
    o.y = fmaxf(d1 * rs * gv.y + bv.y, 0.f);
    o.z = fmaxf(d2 * rs * gv.z + bv.z, 0.f);
    o.w = fmaxf(d3 * rs * gv.w + bv.w, 0.f);
    __syncthreads();
    *(float4*)(&xs[c]) = o;
    __syncthreads();
  }
  // ---- fccls: out_cls = x @ W81 + b (81 cols) ----
  {
    const unsigned short* W = whd + WH_FCCLS;
    float a0 = 0.f, a1 = 0.f;
#pragma unroll 8
    for (int k = kb; k < kb + 64; ++k) {
      float xk = xs[k];
      a0 += xk * bf2f(W[(size_t)k * 81 + lane]);
      if (lane < 17) a1 += xk * bf2f(W[(size_t)k * 81 + 64 + lane]);
    }
    ps[wv][lane] = a0;
    if (lane < 17) ps[wv][64 + lane] = a1;
    __syncthreads();
    if (wv == 0) {
      float s = ps[0][lane] + ps[1][lane] + ps[2][lane] + ps[3][lane];
      out_cls[(size_t)row * 81 + lane] = s + fcclsb[lane];
      if (lane < 17) {
        float s2 = ps[0][64 + lane] + ps[1][64 + lane] + ps[2][64 + lane] + ps[3][64 + lane];
        out_cls[(size_t)row * 81 + 64 + lane] = s2 + fcclsb[64 + lane];
      }
    }
  }
}

// ---------------------------------------------------------------------------
// Phase E: out[b][q][hw] = sum_c mk[b][q][c] * feat[b][c][hw]
// LDS-free; A pre-converted bf16 (mk16), B converted in-flight.
// ---------------------------------------------------------------------------
__global__ __launch_bounds__(256, 4) void phaseE(const unsigned short* __restrict__ mk16,
                                                 const float* __restrict__ feat,
                                                 float* __restrict__ out) {
  int tid = threadIdx.x;
  int b = blockIdx.y;
  int hw0 = blockIdx.x * 128;
  int w = tid >> 6, lane = tid & 63, quad = lane >> 4, l15 = lane & 15;
  f32x4 acc[7][2];
#pragma unroll
  for (int mt = 0; mt < 7; ++mt)
#pragma unroll
    for (int nt = 0; nt < 2; ++nt) {
      acc[mt][nt][0] = 0.f; acc[mt][nt][1] = 0.f; acc[mt][nt][2] = 0.f; acc[mt][nt][3] = 0.f;
    }
  size_t fb = (size_t)b * 256 * 16384;
  int hwl = hw0 + w * 32 + l15;
  const unsigned short* mkb_b = mk16 + (size_t)b * 100 * 256;
  for (int kk = 0; kk < 8; ++kk) {
    bfrag bv[2];
#pragma unroll
    for (int nt = 0; nt < 2; ++nt) {
#pragma unroll
      for (int j = 0; j < 8; ++j) {
        float v = feat[fb + (size_t)(kk * 32 + quad * 8 + j) * 16384 + hwl + nt * 16];
        bv[nt][j] = (short)f2bf(v);
      }
    }
    bfrag av[7];
#pragma unroll
    for (int mt = 0; mt < 7; ++mt) {
      int row = mt * 16 + l15;
      int rr = (row < 100) ? row : 0;  // rows >=100 feed only unstored acc rows
      av[mt] = *(const bfrag*)(mkb_b + (size_t)rr * 256 + kk * 32 + quad * 8);
    }
#pragma unroll
    for (int mt = 0; mt < 7; ++mt) {
      acc[mt][0] = __builtin_amdgcn_mfma_f32_16x16x32_bf16(av[mt], bv[0], acc[mt][0], 0, 0, 0);
      acc[mt][1] = __builtin_amdgcn_mfma_f32_16x16x32_bf16(av[mt], bv[1], acc[mt][1], 0, 0, 0);
    }
  }
#pragma unroll
  for (int mt = 0; mt < 7; ++mt)
#pragma unroll
    for (int nt = 0; nt < 2; ++nt)
#pragma unroll
      for (int r = 0; r < 4; ++r) {
        int m = mt * 16 + quad * 4 + r;
        if (m < 100)
          out[(size_t)(b * 100 + m) * 16384 + hw0 + w * 32 + nt * 16 + l15] = acc[mt][nt][r];
      }
}

// ---------------------------------------------------------------------------
extern "C" void kernel_launch(void* const* d_in, const int* in_sizes, int n_in,
                              void* d_out, int out_size, void* d_ws, size_t ws_size,
                              hipStream_t stream) {
  const float* feat    = (const float*)d_in[0];
  const float* prop    = (const float*)d_in[1];
  const float* maskp   = (const float*)d_in[2];
  const float* fW      = (const float*)d_in[3];
  const float* fb_     = (const float*)d_in[4];
  const float* fng     = (const float*)d_in[5];
  const float* fnb     = (const float*)d_in[6];
  const float* f_ng    = (const float*)d_in[7];
  const float* f_nb    = (const float*)d_in[8];
  const float* kW      = (const float*)d_in[9];
  const float* kb_     = (const float*)d_in[10];
  const float* kng     = (const float*)d_in[11];
  const float* knb     = (const float*)d_in[12];
  const float* k_ng    = (const float*)d_in[13];
  const float* k_nb    = (const float*)d_in[14];
  const float* aw_in   = (const float*)d_in[15];
  const float* ab_in   = (const float*)d_in[16];
  const float* aw_out  = (const float*)d_in[17];
  const float* ab_out  = (const float*)d_in[18];
  const float* s_ng    = (const float*)d_in[19];
  const float* s_nb    = (const float*)d_in[20];
  const float* w1      = (const float*)d_in[21];
  const float* b1      = (const float*)d_in[22];
  const float* w2      = (const float*)d_in[23];
  const float* b2      = (const float*)d_in[24];
  const float* ffn_ng  = (const float*)d_in[25];
  const float* ffn_nb  = (const float*)d_in[26];
  const float* cls_w   = (const float*)d_in[27];
  const float* cls_g   = (const float*)d_in[28];
  const float* cls_b   = (const float*)d_in[29];
  const float* fcclsw  = (const float*)d_in[30];
  const float* fcclsb  = (const float*)d_in[31];
  const float* mask_w  = (const float*)d_in[32];
  const float* mask_g  = (const float*)d_in[33];
  const float* mask_b  = (const float*)d_in[34];
  const float* fcmw    = (const float*)d_in[35];
  const float* fcmb    = (const float*)d_in[36];
  float* out = (float*)d_out;

  // ---- workspace: 32.1 MB total (proven-safe bound is 33.03 MB) ----
  float* ws = (float*)d_ws;
  size_t off = 0;
  unsigned short* wt = (unsigned short*)(ws + off); off += 681984;  // 1,363,968 bf16
  float* fm     = ws + off; off += 204800;
  float* bias_f = ws + off; off += 104;
  float* bias_k = ws + off; off += 104;
  unsigned int* bitsbuf = (unsigned int*)(ws + off); off += 409600;  // 409,600 words
  unsigned short* whd = (unsigned short*)(ws + off); off += 174208;  // 348,416 bf16 head W
  float* partial = ws + off;   // union region: 8*32*100*256 = 6,553,600 floats
  float* ub = partial;
  size_t uo = 0;
  float* wb   = ub + uo; uo += 83200;   // 800 x 104
  float* pt   = ub + uo; uo += 204800;
  float* fbuf = ub + uo; uo += 204800;
  float* kkb  = ub + uo; uo += 204800;
  float* qkvb = ub + uo; uo += 614400;
  float* ob   = ub + uo; uo += 204800;
  float* mo   = ub + uo; uo += 204800;
  float* kk2  = ub + uo; uo += 204800;
  float* t1   = ub + uo; uo += 204800;
  float* objb = ub + uo; uo += 204800;
  float* mkb  = ub + uo; uo += 204800;
  unsigned short* ffn1b = (unsigned short*)(ub + uo); uo += 409600;  // 800x2048 bf16
  unsigned short* mkb16 = (unsigned short*)mkb;  // 800x256 bf16 view

  // Wt sub-offsets (shorts)
  const int wt_fW = 0, wt_kW = 26624, wt_ain = 53248, wt_aout = 249856;
  const int wt_w1 = 315392, wt_w2 = 839680;

  float* out_cls  = out;                       // [800][81]
  float* out_mask = out + 64800;               // [8][100][16384]
  float* out_obj  = out + 64800 + 13107200;    // [800][256]

  // ---- weight prep ----
  Prep6 p;
  const float* srcs[6] = {fW, kW, aw_in, aw_out, w1, w2};
  int Ks[6]    = {256, 256, 256, 256, 256, 2048};
  int Ns[6]    = {103, 103, 768, 256, 2048, 256};
  int doffs[6] = {wt_fW, wt_kW, wt_ain, wt_aout, wt_w1, wt_w2};
  int tb = 0;
  for (int i = 0; i < 6; ++i) {
    p.s[i] = srcs[i]; p.K[i] = Ks[i]; p.N[i] = Ns[i]; p.doff[i] = doffs[i];
    p.base[i] = tb;
    tb += ((Ks[i] + 31) / 32) * ((Ns[i] + 31) / 32);
  }
  prep_w<<<tb, 256, 0, stream>>>(p, wt);
  prep_bias<<<1, 256, 0, stream>>>(fb_, kb_, bias_f, bias_k);
  // head weights -> bf16, original [k][n] layout
  Cast4 cc;
  const float* csrc[4] = {cls_w, fcclsw, mask_w, fcmw};
  int cn[4] = {65536, 20736, 196608, 65536};
  int cdoff[4] = {0, 65536, 86272, 282880};
  int cb = 0;
  for (int i = 0; i < 4; ++i) {
    cc.s[i] = csrc[i]; cc.n[i] = cn[i]; cc.doff[i] = cdoff[i];
    cc.base[i] = cb;
    cb += (cn[i] + 1023) / 1024;
  }
  cast_w<<<cb, 256, 0, stream>>>(cc, whd);
  pack_bits<<<12800, 256, 0, stream>>>(maskp, bitsbuf);

  // f_masked = hard(mask) @ feat^T
  phaseA<<<dim3(32, 2, 8), 512, 0, stream>>>(bitsbuf, feat, partial);
  reduceA<<<800, 256, 0, stream>>>(partial, fm);
  // dysep 1  (partial region reused for activations from here)
  gemm_mf<0, 0><<<dim3(13, 2), 256, 0, stream>>>(prop, wt + wt_fW, bias_f, wb, 800, 256, 103, 104, 0);
  pointdw<<<dim3(8, 8), 256, 0, stream>>>(fm, wb, pt);
  ln2_kernel<<<200, 256, 0, stream>>>(pt, fm, fng, fnb, f_ng, f_nb, fbuf);
  // dysep 2
  gemm_mf<0, 0><<<dim3(13, 2), 256, 0, stream>>>(prop, wt + wt_kW, bias_k, wb, 800, 256, 103, 104, 0);
  pointdw<<<dim3(8, 8), 256, 0, stream>>>(fbuf, wb, pt);
  ln2_kernel<<<200, 256, 0, stream>>>(pt, fbuf, kng, knb, k_ng, k_nb, kkb);
  // MHA
  gemm_mf<0, 0><<<dim3(13, 12), 256, 0, stream>>>(kkb, wt + wt_ain, ab_in, qkvb, 800, 256, 768, 768, 0);
  attn_kernel<<<dim3(8, 8), 256, 0, stream>>>(qkvb, ob);
  gemm_mf<0, 0><<<dim3(13, 4), 256, 0, stream>>>(ob, wt + wt_aout, ab_out, mo, 800, 256, 256, 256, 0);
  ln_kernel<<<200, 256, 0, stream>>>(mo, kkb, s_ng, s_nb, kk2, 0, nullptr);
  // FFN
  gemm_mf<0, 1><<<dim3(13, 32), 256, 0, stream>>>(kk2, wt + wt_w1, b1, ffn1b, 800, 256, 2048, 2048, 1);
  gemm_mf<1, 0><<<dim3(13, 4), 256, 0, stream>>>(ffn1b, wt + wt_w2, b2, t1, 800, 2048, 256, 256, 0);
  ln_kernel<<<200, 256, 0, stream>>>(t1, kk2, ffn_ng, ffn_nb, objb, 0, out_obj);
  // fused cls + mask head (row-per-block, k-split waves, bf16 weights)
  head_fused<<<800, 256, 0, stream>>>(objb, whd, cls_g, cls_b, fcclsb,
                                      mask_g, mask_b, fcmb, out_cls, mkb16);
  // new_mask_preds = mk @ feat
  phaseE<<<dim3(128, 8), 256, 0, stream>>>(mkb16, feat, out_mask);
}

// Round 5
// 587.986 us; speedup vs baseline: 1.4417x; 1.1154x over previous
//
#include <hip/hip_runtime.h>

typedef float f32x4 __attribute__((ext_vector_type(4)));
typedef short bfrag __attribute__((ext_vector_type(8)));
typedef short sh4 __attribute__((ext_vector_type(4)));

__device__ __forceinline__ unsigned short f2bf(float x) {
  unsigned int u = __float_as_uint(x);
  return (unsigned short)((u + 0x7FFFu + ((u >> 16) & 1u)) >> 16);
}
__device__ __forceinline__ float bf2f(unsigned short u) {
  return __uint_as_float(((unsigned int)u) << 16);
}
__device__ __forceinline__ float wred_sum(float v) {
#pragma unroll
  for (int o = 32; o > 0; o >>= 1) v += __shfl_xor(v, o);
  return v;
}
__device__ __forceinline__ float wred_max(float v) {
#pragma unroll
  for (int o = 32; o > 0; o >>= 1) v = fmaxf(v, __shfl_xor(v, o));
  return v;
}

// ---------------------------------------------------------------------------
// Weight prep: Wt[n][k] (bf16, k-contiguous) = W[k][n].
// fW at rows 0..103, kW at rows 104..207 (both pw/dw col-permuted) -> the two
// dysep weight GEMMs fuse into one N=208 GEMM.
// ---------------------------------------------------------------------------
struct Prep6 {
  const float* s[6];
  int K[6];
  int N[6];
  int base[6];
  int doff[6];
};

__global__ __launch_bounds__(256) void prep_w(Prep6 p, unsigned short* wt) {
  int t = blockIdx.x;
  int wi = 0;
#pragma unroll
  for (int i = 0; i < 5; ++i)
    if (t >= p.base[i + 1]) wi = i + 1;
  int lt = t - p.base[wi];
  int K = p.K[wi], N = p.N[wi];
  int tkn = (K + 31) >> 5;
  int tk = lt % tkn, tn = lt / tkn;
  __shared__ float tile[32][33];
  const float* src = p.s[wi];
#pragma unroll
  for (int i = 0; i < 4; ++i) {
    int flat = i * 256 + threadIdx.x;
    int kl = flat >> 5, nl = flat & 31;
    int k = tk * 32 + kl, n = tn * 32 + nl;
    tile[kl][nl] = (k < K && n < N) ? src[(size_t)k * N + n] : 0.f;
  }
  __syncthreads();
  unsigned short* dst = wt + p.doff[wi];
#pragma unroll
  for (int i = 0; i < 4; ++i) {
    int flat = i * 256 + threadIdx.x;
    int nl = flat >> 5, kl = flat & 31;
    int k = tk * 32 + kl, n = tn * 32 + nl;
    if (k < K && n < N) {
      int np = (wi < 2) ? ((n >= 3) ? n - 3 : n + 100) : n;
      dst[(size_t)np * K + k] = f2bf(tile[kl][nl]);
    }
  }
}

// bias_fk[208]: [0..103] = fb permuted, [104..207] = kb permuted
__global__ __launch_bounds__(256) void prep_bias(const float* __restrict__ fb_,
                                                 const float* __restrict__ kb_,
                                                 float* __restrict__ bfk) {
  int t = threadIdx.x;
  if (t < 103) {
    int np = (t >= 3) ? t - 3 : t + 100;
    bfk[np] = fb_[t];
    bfk[104 + np] = kb_[t];
  }
  if (t == 103) { bfk[103] = 0.f; bfk[207] = 0.f; }
}

// ---------------------------------------------------------------------------
// cast_w: head weights f32 -> bf16, original [k][n] layout (no transpose).
// ---------------------------------------------------------------------------
struct Cast4 {
  const float* s[4];
  int n[4];
  int base[4];
  int doff[4];
};

__global__ __launch_bounds__(256) void cast_w(Cast4 cc, unsigned short* dst) {
  int t = blockIdx.x;
  int wi = 0;
#pragma unroll
  for (int i = 0; i < 3; ++i)
    if (t >= cc.base[i + 1]) wi = i + 1;
  int lt = t - cc.base[wi];
  int idx = lt * 1024 + threadIdx.x * 4;
  if (idx + 3 < cc.n[wi]) {
    float4 v = *(const float4*)(cc.s[wi] + idx);
    sh4 o;
    o[0] = (short)f2bf(v.x); o[1] = (short)f2bf(v.y);
    o[2] = (short)f2bf(v.z); o[3] = (short)f2bf(v.w);
    *(sh4*)(dst + cc.doff[wi] + idx) = o;
  }
}

// ---------------------------------------------------------------------------
// pack_bits: hard mask (mask>0) packed 1 bit/elem.
// ---------------------------------------------------------------------------
__global__ __launch_bounds__(256) void pack_bits(const float* __restrict__ mask,
                                                 unsigned int* __restrict__ bits) {
  int tid = threadIdx.x;
  size_t f = (size_t)blockIdx.x * 256 + tid;
  float4 m = *(const float4*)(mask + f * 4);
  unsigned int n = (m.x > 0.f ? 1u : 0u) | (m.y > 0.f ? 2u : 0u) |
                   (m.z > 0.f ? 4u : 0u) | (m.w > 0.f ? 8u : 0u);
  n <<= ((tid & 7) * 4);
  n |= (unsigned int)__shfl_xor((int)n, 1);
  n |= (unsigned int)__shfl_xor((int)n, 2);
  n |= (unsigned int)__shfl_xor((int)n, 4);
  if ((tid & 7) == 0) bits[((size_t)blockIdx.x * 32) + (tid >> 3)] = n;
}

// ---------------------------------------------------------------------------
// MFMA GEMM: C[m][n] = act(sum_k A[m][k] * Wt[n][k] + bias[n]), row stride ldc
// K-slab support: blockIdx.z picks k-range [z*kspan, (z+1)*kspan); output goes
// to slab z (offset z*M*ldc). Normal calls: grid z=1, kspan=K.
// ---------------------------------------------------------------------------
template <int ABF, int OBF>
__global__ __launch_bounds__(256) void gemm_mf(const void* Av,
                                               const unsigned short* __restrict__ Wt,
                                               const float* __restrict__ bias,
                                               void* Cv, int M, int K, int N, int ldc, int relu,
                                               int kspan) {
  __shared__ short Al[64 * 72];
  __shared__ short Wl[64 * 72];
  int tid = threadIdx.x;
  int r0 = blockIdx.x * 64;
  int c0 = blockIdx.y * 64;
  int kz = blockIdx.z * kspan;
  int w = tid >> 6, lane = tid & 63, quad = lane >> 4, l15 = lane & 15;

  f32x4 acc[4];
#pragma unroll
  for (int mt = 0; mt < 4; ++mt) {
    acc[mt][0] = 0.f; acc[mt][1] = 0.f; acc[mt][2] = 0.f; acc[mt][3] = 0.f;
  }

  for (int k0 = kz; k0 < kz + kspan; k0 += 64) {
    if (ABF) {
      const unsigned short* A = (const unsigned short*)Av;
#pragma unroll
      for (int p = 0; p < 2; ++p) {
        int flat = p * 256 + tid;
        int row = flat >> 3, k8 = flat & 7;
        bfrag v;
        if (r0 + row < M)
          v = *(const bfrag*)(A + (size_t)(r0 + row) * K + k0 + k8 * 8);
        else
          v = (bfrag)(short)0;
        *(bfrag*)(Al + row * 72 + k8 * 8) = v;
      }
    } else {
      const float* A = (const float*)Av;
#pragma unroll
      for (int p = 0; p < 4; ++p) {
        int flat = p * 256 + tid;
        int row = flat >> 4, c4 = flat & 15;
        sh4 o4;
        if (r0 + row < M) {
          float4 v = *(const float4*)(A + (size_t)(r0 + row) * K + k0 + c4 * 4);
          o4[0] = (short)f2bf(v.x); o4[1] = (short)f2bf(v.y);
          o4[2] = (short)f2bf(v.z); o4[3] = (short)f2bf(v.w);
        } else {
          o4[0] = 0; o4[1] = 0; o4[2] = 0; o4[3] = 0;
        }
        *(sh4*)(Al + row * 72 + c4 * 4) = o4;
      }
    }
#pragma unroll
    for (int p = 0; p < 2; ++p) {
      int flat = p * 256 + tid;
      int row = flat >> 3, k8 = flat & 7;
      bfrag v;
      if (c0 + row < N)
        v = *(const bfrag*)(Wt + (size_t)(c0 + row) * K + k0 + k8 * 8);
      else
        v = (bfrag)(short)0;
      *(bfrag*)(Wl + row * 72 + k8 * 8) = v;
    }
    __syncthreads();
#pragma unroll
    for (int kk = 0; kk < 2; ++kk) {
      bfrag bv = *(const bfrag*)(Wl + (w * 16 + l15) * 72 + kk * 32 + quad * 8);
#pragma unroll
      for (int mt = 0; mt < 4; ++mt) {
        bfrag av = *(const bfrag*)(Al + (mt * 16 + l15) * 72 + kk * 32 + quad * 8);
        acc[mt] = __builtin_amdgcn_mfma_f32_16x16x32_bf16(av, bv, acc[mt], 0, 0, 0);
      }
    }
    __syncthreads();
  }
  int col = c0 + w * 16 + l15;
  if (col < N) {
    float bv = bias ? bias[col] : 0.f;
    size_t zoff = (size_t)blockIdx.z * M * ldc;
#pragma unroll
    for (int mt = 0; mt < 4; ++mt)
#pragma unroll
      for (int r = 0; r < 4; ++r) {
        int m = r0 + mt * 16 + quad * 4 + r;
        if (m < M) {
          float v = acc[mt][r] + bv;
          if (relu) v = fmaxf(v, 0.f);
          if (OBF)
            ((unsigned short*)Cv)[zoff + (size_t)m * ldc + col] = f2bf(v);
          else
            ((float*)Cv)[zoff + (size_t)m * ldc + col] = v;
        }
      }
  }
}

// ---------------------------------------------------------------------------
// Phase A: partial[b][ks][m][c] += hard(mask)·feat; A-tile from packed bits.
// (frozen — measured-good)
// ---------------------------------------------------------------------------
__global__ __launch_bounds__(512, 4) void phaseA(const unsigned int* __restrict__ bits,
                                                 const float* __restrict__ feat,
                                                 float* __restrict__ partial) {
  int tid = threadIdx.x;
  int ks = blockIdx.x;  // 0..31
  int ct = blockIdx.y;  // 0..1
  int b  = blockIdx.z;  // 0..7
  __shared__ short Al[2][112 * 72];
  __shared__ short Bl[2][128 * 72];
  int w = tid >> 6, lane = tid & 63, quad = lane >> 4, l15 = lane & 15;

  int rbase = tid >> 4;
  int c4 = tid & 15;
  const float* frow = feat + (size_t)(b * 256 + ct * 128 + rbase) * 16384 + c4 * 4;

  int arow = tid >> 2, q = tid & 3;
  bool aact = tid < 400;
  const unsigned int* brow = bits + (size_t)(b * 100 + arow) * 512 + (q >> 1);

  f32x4 acc[7];
#pragma unroll
  for (int mt = 0; mt < 7; ++mt) {
    acc[mt][0] = 0.f; acc[mt][1] = 0.f; acc[mt][2] = 0.f; acc[mt][3] = 0.f;
  }

  for (int z = tid; z < 384; z += 512) {
    int bufi = z / 192, rem = z % 192;
    sh4 zz; zz[0] = 0; zz[1] = 0; zz[2] = 0; zz[3] = 0;
    *(sh4*)(&Al[bufi][(100 + (rem >> 4)) * 72 + (rem & 15) * 4]) = zz;
  }

  int k0 = ks * 512;
  {
    float4 bpf[4];
    unsigned int awd = 0;
#pragma unroll
    for (int p = 0; p < 4; ++p)
      bpf[p] = *(const float4*)(frow + (size_t)p * 32 * 16384 + k0);
    if (aact) awd = brow[k0 >> 5];
#pragma unroll
    for (int p = 0; p < 4; ++p) {
      int row = rbase + 32 * p;
      sh4 o4b;
      o4b[0] = (short)f2bf(bpf[p].x);
      o4b[1] = (short)f2bf(bpf[p].y);
      o4b[2] = (short)f2bf(bpf[p].z);
      o4b[3] = (short)f2bf(bpf[p].w);
      *(sh4*)(&Bl[0][row * 72 + c4 * 4]) = o4b;
    }
    if (aact) {
      unsigned int hw16 = (awd >> ((q & 1) * 16)) & 0xFFFFu;
      bfrag e0, e1;
#pragma unroll
      for (int i = 0; i < 8; ++i) e0[i] = ((hw16 >> i) & 1u) ? (short)0x3F80 : (short)0;
#pragma unroll
      for (int i = 0; i < 8; ++i) e1[i] = ((hw16 >> (i + 8)) & 1u) ? (short)0x3F80 : (short)0;
      *(bfrag*)(&Al[0][arow * 72 + q * 16]) = e0;
      *(bfrag*)(&Al[0][arow * 72 + q * 16 + 8]) = e1;
    }
  }
  __syncthreads();

  int cur = 0;
  for (int st = 0; st < 8; ++st) {
    float4 bpf[4];
    unsigned int awd = 0;
    if (st < 7) {
      int kb = k0 + (st + 1) * 64;
#pragma unroll
      for (int p = 0; p < 4; ++p)
        bpf[p] = *(const float4*)(frow + (size_t)p * 32 * 16384 + kb);
      if (aact) awd = brow[kb >> 5];
    }
#pragma unroll
    for (int kk = 0; kk < 2; ++kk) {
      bfrag bv = *(const bfrag*)(&Bl[cur][(w * 16 + l15) * 72 + kk * 32 + quad * 8]);
#pragma unroll
      for (int mt = 0; mt < 7; ++mt) {
        bfrag av = *(const bfrag*)(&Al[cur][(mt * 16 + l15) * 72 + kk * 32 + quad * 8]);
        acc[mt] = __builtin_amdgcn_mfma_f32_16x16x32_bf16(av, bv, acc[mt], 0, 0, 0);
      }
    }
    __builtin_amdgcn_sched_barrier(0);
    if (st < 7) {
      int nxt = cur ^ 1;
#pragma unroll
      for (int p = 0; p < 4; ++p) {
        int row = rbase + 32 * p;
        sh4 o4b;
        o4b[0] = (short)f2bf(bpf[p].x);
        o4b[1] = (short)f2bf(bpf[p].y);
        o4b[2] = (short)f2bf(bpf[p].z);
        o4b[3] = (short)f2bf(bpf[p].w);
        *(sh4*)(&Bl[nxt][row * 72 + c4 * 4]) = o4b;
      }
      if (aact) {
        unsigned int hw16 = (awd >> ((q & 1) * 16)) & 0xFFFFu;
        bfrag e0, e1;
#pragma unroll
        for (int i = 0; i < 8; ++i) e0[i] = ((hw16 >> i) & 1u) ? (short)0x3F80 : (short)0;
#pragma unroll
        for (int i = 0; i < 8; ++i) e1[i] = ((hw16 >> (i + 8)) & 1u) ? (short)0x3F80 : (short)0;
        *(bfrag*)(&Al[nxt][arow * 72 + q * 16]) = e0;
        *(bfrag*)(&Al[nxt][arow * 72 + q * 16 + 8]) = e1;
      }
    }
    __syncthreads();
    cur ^= 1;
  }

  float* pb = partial + (size_t)(b * 32 + ks) * (100 * 256) + ct * 128 + w * 16 + l15;
#pragma unroll
  for (int mt = 0; mt < 7; ++mt)
#pragma unroll
    for (int r = 0; r < 4; ++r) {
      int m = mt * 16 + quad * 4 + r;
      if (m < 100) pb[(size_t)m * 256] = acc[mt][r];
    }
}

__global__ __launch_bounds__(256) void reduceA(const float* __restrict__ partial,
                                               float* __restrict__ fm) {
  int gid = blockIdx.x * 256 + threadIdx.x;
  int c = gid & 255, row = gid >> 8;
  int b = row / 100, n = row % 100;
  float s = 0.f;
#pragma unroll
  for (int ks = 0; ks < 32; ++ks)
    s += partial[((size_t)(b * 32 + ks) * 100 + n) * 256 + c];
  fm[(size_t)row * 256 + c] = s;
}

// ---------------------------------------------------------------------------
// dysep middle: wbuf rows (stride 208): [fW: pw(100)|dw(3)|pad | kW: pw|dw|pad]
// caller passes wbuf (dysep1) or wbuf+104 (dysep2).
// ---------------------------------------------------------------------------
__global__ __launch_bounds__(256) void pointdw(const float* __restrict__ fm,
                                               const float* __restrict__ wbuf,
                                               float* __restrict__ point) {
  int tid = threadIdx.x;
  int b = blockIdx.y, c0 = blockIdx.x * 32;
  __shared__ float dl[100 * 33];
  for (int flat = tid; flat < 3200; flat += 256) {
    int n = flat >> 5, cl = flat & 31, c = c0 + cl;
    const float* fr = fm + (size_t)(b * 100 + n) * 256;
    const float* wr = wbuf + (size_t)(b * 100 + n) * 208;
    float x0 = (c > 0) ? fr[c - 1] : 0.f;
    float x1 = fr[c];
    float x2 = (c < 255) ? fr[c + 1] : 0.f;
    float d = wr[100] * x0 + wr[101] * x1 + wr[102] * x2;
    dl[n * 33 + cl] = fmaxf(d, 0.f);
  }
  __syncthreads();
  int cl = tid & 31, mg = tid >> 5;
  for (int m = mg; m < 100; m += 8) {
    const float4* pw4 = (const float4*)(wbuf + (size_t)(b * 100 + m) * 208);
    float a = 0.f;
#pragma unroll
    for (int n4 = 0; n4 < 25; ++n4) {
      float4 wv = pw4[n4];
      a += wv.x * dl[(n4 * 4 + 0) * 33 + cl] + wv.y * dl[(n4 * 4 + 1) * 33 + cl]
         + wv.z * dl[(n4 * 4 + 2) * 33 + cl] + wv.w * dl[(n4 * 4 + 3) * 33 + cl];
    }
    point[(size_t)(b * 100 + m) * 256 + c0 + cl] = a;
  }
}

// ---------------------------------------------------------------------------
__global__ __launch_bounds__(256) void ln2_kernel(const float* __restrict__ x,
                                                  const float* __restrict__ resid,
                                                  const float* __restrict__ g1, const float* __restrict__ b1,
                                                  const float* __restrict__ g2, const float* __restrict__ b2,
                                                  float* __restrict__ out) {
  int tid = threadIdx.x;
  int row = blockIdx.x * 4 + (tid >> 6);
  int lane = tid & 63;
  size_t base = (size_t)row * 256 + lane * 4;
  float4 v = *(const float4*)(x + base);
  float mean = wred_sum(v.x + v.y + v.z + v.w) * (1.f / 256.f);
  float d0 = v.x - mean, d1 = v.y - mean, d2 = v.z - mean, d3 = v.w - mean;
  float rs = rsqrtf(wred_sum(d0 * d0 + d1 * d1 + d2 * d2 + d3 * d3) * (1.f / 256.f) + 1e-5f);
  float4 gv = *(const float4*)(g1 + lane * 4);
  float4 bv = *(const float4*)(b1 + lane * 4);
  float4 rv = *(const float4*)(resid + base);
  float y0 = rv.x + d0 * rs * gv.x + bv.x;
  float y1 = rv.y + d1 * rs * gv.y + bv.y;
  float y2 = rv.z + d2 * rs * gv.z + bv.z;
  float y3 = rv.w + d3 * rs * gv.w + bv.w;
  float mean2 = wred_sum(y0 + y1 + y2 + y3) * (1.f / 256.f);
  float e0 = y0 - mean2, e1 = y1 - mean2, e2 = y2 - mean2, e3 = y3 - mean2;
  float rs2 = rsqrtf(wred_sum(e0 * e0 + e1 * e1 + e2 * e2 + e3 * e3) * (1.f / 256.f) + 1e-5f);
  float4 g2v = *(const float4*)(g2 + lane * 4);
  float4 b2v = *(const float4*)(b2 + lane * 4);
  float4 o;
  o.x = e0 * rs2 * g2v.x + b2v.x;
  o.y = e1 * rs2 * g2v.y + b2v.y;
  o.z = e2 * rs2 * g2v.z + b2v.z;
  o.w = e3 * rs2 * g2v.w + b2v.w;
  *(float4*)(out + base) = o;
}

__global__ __launch_bounds__(256) void ln_kernel(const float* __restrict__ x,
                                                 const float* __restrict__ res,
                                                 const float* __restrict__ g, const float* __restrict__ bb,
                                                 float* __restrict__ out, int relu,
                                                 float* __restrict__ copy2) {
  int tid = threadIdx.x;
  int row = blockIdx.x * 4 + (tid >> 6);
  int lane = tid & 63;
  size_t base = (size_t)row * 256 + lane * 4;
  float4 v = *(const float4*)(x + base);
  if (res) {
    float4 rv = *(const float4*)(res + base);
    v.x += rv.x; v.y += rv.y; v.z += rv.z; v.w += rv.w;
  }
  float mean = wred_sum(v.x + v.y + v.z + v.w) * (1.f / 256.f);
  float d0 = v.x - mean, d1 = v.y - mean, d2 = v.z - mean, d3 = v.w - mean;
  float rs = rsqrtf(wred_sum(d0 * d0 + d1 * d1 + d2 * d2 + d3 * d3) * (1.f / 256.f) + 1e-5f);
  float4 gv = *(const float4*)(g + lane * 4);
  float4 bv = *(const float4*)(bb + lane * 4);
  float4 o;
  o.x = d0 * rs * gv.x + bv.x;
  o.y = d1 * rs * gv.y + bv.y;
  o.z = d2 * rs * gv.z + bv.z;
  o.w = d3 * rs * gv.w + bv.w;
  if (relu) {
    o.x = fmaxf(o.x, 0.f); o.y = fmaxf(o.y, 0.f);
    o.z = fmaxf(o.z, 0.f); o.w = fmaxf(o.w, 0.f);
  }
  *(float4*)(out + base) = o;
  if (copy2) *(float4*)(copy2 + base) = o;
}

// ---------------------------------------------------------------------------
// ln_ffn2: v = sum of 4 k-split GEMM slabs + b2 + residual -> LN -> out (+copy)
// ---------------------------------------------------------------------------
__global__ __launch_bounds__(256) void ln_ffn2(const float* __restrict__ t1,
                                               const float* __restrict__ b2,
                                               const float* __restrict__ res,
                                               const float* __restrict__ g, const float* __restrict__ bb,
                                               float* __restrict__ out,
                                               float* __restrict__ copy2) {
  int tid = threadIdx.x;
  int row = blockIdx.x * 4 + (tid >> 6);
  int lane = tid & 63;
  size_t base = (size_t)row * 256 + lane * 4;
  float4 v = *(const float4*)(t1 + base);
#pragma unroll
  for (int s = 1; s < 4; ++s) {
    float4 p = *(const float4*)(t1 + (size_t)s * 204800 + base);
    v.x += p.x; v.y += p.y; v.z += p.z; v.w += p.w;
  }
  float4 b2v = *(const float4*)(b2 + lane * 4);
  float4 rv = *(const float4*)(res + base);
  v.x += b2v.x + rv.x; v.y += b2v.y + rv.y; v.z += b2v.z + rv.z; v.w += b2v.w + rv.w;
  float mean = wred_sum(v.x + v.y + v.z + v.w) * (1.f / 256.f);
  float d0 = v.x - mean, d1 = v.y - mean, d2 = v.z - mean, d3 = v.w - mean;
  float rs = rsqrtf(wred_sum(d0 * d0 + d1 * d1 + d2 * d2 + d3 * d3) * (1.f / 256.f) + 1e-5f);
  float4 gv = *(const float4*)(g + lane * 4);
  float4 bv = *(const float4*)(bb + lane * 4);
  float4 o;
  o.x = d0 * rs * gv.x + bv.x;
  o.y = d1 * rs * gv.y + bv.y;
  o.z = d2 * rs * gv.z + bv.z;
  o.w = d3 * rs * gv.w + bv.w;
  *(float4*)(out + base) = o;
  *(float4*)(copy2 + base) = o;
}

// ---------------------------------------------------------------------------
// MHA v2: one block per (head, batch, q-quarter). 256 blocks (was 64).
// sl shrinks to 25x100 -> 29 KB LDS total.
// ---------------------------------------------------------------------------
__global__ __launch_bounds__(256) void attn_kernel(const float* __restrict__ qkv,
                                                   float* __restrict__ obuf) {
  int tid = threadIdx.x;
  int b = blockIdx.y, h = blockIdx.x & 7, qq = blockIdx.x >> 3;
  __shared__ float ktj[100 * 32];          // k [j][dd]
  __shared__ unsigned short vl[100 * 32];  // v bf16 [j][dd]
  __shared__ float sl[25 * 100];
  const float* base = qkv + (size_t)b * 100 * 768;
  for (int flat = tid; flat < 3200; flat += 256) {
    int j = flat >> 5, dd = flat & 31;
    ktj[j * 32 + dd] = base[(size_t)j * 768 + 256 + h * 32 + dd];
    vl[j * 32 + dd] = f2bf(base[(size_t)j * 768 + 512 + h * 32 + dd]);
  }
  __syncthreads();
  {
    int il = tid % 25;       // local q row 0..24
    int jseg = tid / 25;     // 0..10 (only 0..9 active)
    int i = qq * 25 + il;
    const float4* q4 = (const float4*)(base + (size_t)i * 768 + h * 32);
    float4 q[8];
#pragma unroll
    for (int d4 = 0; d4 < 8; ++d4) q[d4] = q4[d4];
    if (jseg < 10) {
      for (int jj = 0; jj < 10; ++jj) {
        int j = jseg * 10 + jj;
        const float4* kr = (const float4*)(ktj + j * 32);
        float a = 0.f;
#pragma unroll
        for (int d4 = 0; d4 < 8; ++d4) {
          float4 kv = kr[d4];
          a += q[d4].x * kv.x + q[d4].y * kv.y + q[d4].z * kv.z + q[d4].w * kv.w;
        }
        sl[il * 100 + j] = a * 0.17677669529663687f;
      }
    }
  }
  __syncthreads();
  int w = tid >> 6, lane = tid & 63;
  for (int r = w; r < 25; r += 4) {
    float x0 = sl[r * 100 + lane];
    float x1 = (lane + 64 < 100) ? sl[r * 100 + lane + 64] : -1e30f;
    float mx = wred_max(fmaxf(x0, x1));
    float e0 = __expf(x0 - mx);
    float e1 = (lane + 64 < 100) ? __expf(x1 - mx) : 0.f;
    float inv = 1.f / wred_sum(e0 + e1);
    sl[r * 100 + lane] = e0 * inv;
    if (lane + 64 < 100) sl[r * 100 + lane + 64] = e1 * inv;
  }
  __syncthreads();
  for (int flat = tid; flat < 800; flat += 256) {
    int il = flat >> 5, dd = flat & 31;
    float a = 0.f;
#pragma unroll 4
    for (int j = 0; j < 100; ++j) a += sl[il * 100 + j] * bf2f(vl[j * 32 + dd]);
    obuf[(size_t)(b * 100 + qq * 25 + il) * 256 + h * 32 + dd] = a;
  }
}

// ---------------------------------------------------------------------------
// Fused cls + mask head: one row per block (800 blocks, 4 waves, k-split).
// (frozen — measured-good)
// ---------------------------------------------------------------------------
__global__ __launch_bounds__(256) void head_fused(
    const float* __restrict__ objb,
    const unsigned short* __restrict__ whd,
    const float* __restrict__ cls_g, const float* __restrict__ cls_b,
    const float* __restrict__ fcclsb,
    const float* __restrict__ mask_g, const float* __restrict__ mask_b,
    const float* __restrict__ fcmb,
    float* __restrict__ out_cls, unsigned short* __restrict__ mk16) {
  const int WH_CLS = 0, WH_FCCLS = 65536, WH_M = 86272, WH_FCM = 282880;
  int tid = threadIdx.x, wv = tid >> 6, lane = tid & 63;
  int row = blockIdx.x;
  __shared__ float xs[256];
  __shared__ float x0s[256];
  __shared__ float ps[4][256];
  if (wv == 0) {
    float4 v = *(const float4*)(objb + (size_t)row * 256 + lane * 4);
    *(float4*)(&xs[lane * 4]) = v;
    *(float4*)(&x0s[lane * 4]) = v;
  }
  __syncthreads();
  int c = lane * 4;
  int kb = wv * 64;

  for (int li = 0; li < 3; ++li) {
    const unsigned short* W = whd + WH_M + li * 65536;
    float a0 = 0.f, a1 = 0.f, a2 = 0.f, a3 = 0.f;
#pragma unroll 8
    for (int k = kb; k < kb + 64; ++k) {
      float xk = xs[k];
      sh4 w4 = *(const sh4*)(W + (size_t)k * 256 + c);
      a0 += xk * bf2f((unsigned short)w4[0]);
      a1 += xk * bf2f((unsigned short)w4[1]);
      a2 += xk * bf2f((unsigned short)w4[2]);
      a3 += xk * bf2f((unsigned short)w4[3]);
    }
    ps[wv][c] = a0; ps[wv][c + 1] = a1; ps[wv][c + 2] = a2; ps[wv][c + 3] = a3;
    __syncthreads();
    float s0 = ps[0][c] + ps[1][c] + ps[2][c] + ps[3][c];
    float s1 = ps[0][c + 1] + ps[1][c + 1] + ps[2][c + 1] + ps[3][c + 1];
    float s2 = ps[0][c + 2] + ps[1][c + 2] + ps[2][c + 2] + ps[3][c + 2];
    float s3 = ps[0][c + 3] + ps[1][c + 3] + ps[2][c + 3] + ps[3][c + 3];
    float mean = wred_sum(s0 + s1 + s2 + s3) * (1.f / 256.f);
    float d0 = s0 - mean, d1 = s1 - mean, d2 = s2 - mean, d3 = s3 - mean;
    float rs = rsqrtf(wred_sum(d0 * d0 + d1 * d1 + d2 * d2 + d3 * d3) * (1.f / 256.f) + 1e-5f);
    float4 gv = *(const float4*)(mask_g + li * 256 + c);
    float4 bv = *(const float4*)(mask_b + li * 256 + c);
    float4 o;
    o.x = fmaxf(d0 * rs * gv.x + bv.x, 0.f);
    o.y = fmaxf(d1 * rs * gv.y + bv.y, 0.f);
    o.z = fmaxf(d2 * rs * gv.z + bv.z, 0.f);
    o.w = fmaxf(d3 * rs * gv.w + bv.w, 0.f);
    __syncthreads();
    *(float4*)(&xs[c]) = o;
    __syncthreads();
  }
  {
    const unsigned short* W = whd + WH_FCM;
    float a0 = 0.f, a1 = 0.f, a2 = 0.f, a3 = 0.f;
#pragma unroll 8
    for (int k = kb; k < kb + 64; ++k) {
      float xk = xs[k];
      sh4 w4 = *(const sh4*)(W + (size_t)k * 256 + c);
      a0 += xk * bf2f((unsigned short)w4[0]);
      a1 += xk * bf2f((unsigned short)w4[1]);
      a2 += xk * bf2f((unsigned short)w4[2]);
      a3 += xk * bf2f((unsigned short)w4[3]);
    }
    ps[wv][c] = a0; ps[wv][c + 1] = a1; ps[wv][c + 2] = a2; ps[wv][c + 3] = a3;
    __syncthreads();
    if (wv == 0) {
      float s0 = ps[0][c] + ps[1][c] + ps[2][c] + ps[3][c];
      float s1 = ps[0][c + 1] + ps[1][c + 1] + ps[2][c + 1] + ps[3][c + 1];
      float s2 = ps[0][c + 2] + ps[1][c + 2] + ps[2][c + 2] + ps[3][c + 2];
      float s3 = ps[0][c + 3] + ps[1][c + 3] + ps[2][c + 3] + ps[3][c + 3];
      float4 bv = *(const float4*)(fcmb + c);
      sh4 o;
      o[0] = (short)f2bf(s0 + bv.x); o[1] = (short)f2bf(s1 + bv.y);
      o[2] = (short)f2bf(s2 + bv.z); o[3] = (short)f2bf(s3 + bv.w);
      *(sh4*)(mk16 + (size_t)row * 256 + c) = o;
    }
    __syncthreads();
  }
  {
    const unsigned short* W = whd + WH_CLS;
    float a0 = 0.f, a1 = 0.f, a2 = 0.f, a3 = 0.f;
#pragma unroll 8
    for (int k = kb; k < kb + 64; ++k) {
      float xk = x0s[k];
      sh4 w4 = *(const sh4*)(W + (size_t)k * 256 + c);
      a0 += xk * bf2f((unsigned short)w4[0]);
      a1 += xk * bf2f((unsigned short)w4[1]);
      a2 += xk * bf2f((unsigned short)w4[2]);
      a3 += xk * bf2f((unsigned short)w4[3]);
    }
    ps[wv][c] = a0; ps[wv][c + 1] = a1; ps[wv][c + 2] = a2; ps[wv][c + 3] = a3;
    __syncthreads();
    float s0 = ps[0][c] + ps[1][c] + ps[2][c] + ps[3][c];
    float s1 = ps[0][c + 1] + ps[1][c + 1] + ps[2][c + 1] + ps[3][c + 1];
    float s2 = ps[0][c + 2] + ps[1][c + 2] + ps[2][c + 2] + ps[3][c + 2];
    float s3 = ps[0][c + 3] + ps[1][c + 3] + ps[2][c + 3] + ps[3][c + 3];
    float mean = wred_sum(s0 + s1 + s2 + s3) * (1.f / 256.f);
    float d0 = s0 - mean, d1 = s1 - mean, d2 = s2 - mean, d3 = s3 - mean;
    float rs = rsqrtf(wred_sum(d0 * d0 + d1 * d1 + d2 * d2 + d3 * d3) * (1.f / 256.f) + 1e-5f);
    float4 gv = *(const float4*)(cls_g + c);
    float4 bv = *(const float4*)(cls_b + c);
    float4 o;
    o.x = fmaxf(d0 * rs * gv.x + bv.x, 0.f);
    o.y = fmaxf(d1 * rs * gv.y + bv.y, 0.f);
    o.z = fmaxf(d2 * rs * gv.z + bv.z, 0.f);
    o.w = fmaxf(d3 * rs * gv.w + bv.w, 0.f);
    __syncthreads();
    *(float4*)(&xs[c]) = o;
    __syncthreads();
  }
  {
    const unsigned short* W = whd + WH_FCCLS;
    float a0 = 0.f, a1 = 0.f;
#pragma unroll 8
    for (int k = kb; k < kb + 64; ++k) {
      float xk = xs[k];
      a0 += xk * bf2f(W[(size_t)k * 81 + lane]);
      if (lane < 17) a1 += xk * bf2f(W[(size_t)k * 81 + 64 + lane]);
    }
    ps[wv][lane] = a0;
    if (lane < 17) ps[wv][64 + lane] = a1;
    __syncthreads();
    if (wv == 0) {
      float s = ps[0][lane] + ps[1][lane] + ps[2][lane] + ps[3][lane];
      out_cls[(size_t)row * 81 + lane] = s + fcclsb[lane];
      if (lane < 17) {
        float s2 = ps[0][64 + lane] + ps[1][64 + lane] + ps[2][64 + lane] + ps[3][64 + lane];
        out_cls[(size_t)row * 81 + 64 + lane] = s2 + fcclsb[64 + lane];
      }
    }
  }
}

// ---------------------------------------------------------------------------
// Phase E: out[b][q][hw] = sum_c mk[b][q][c] * feat[b][c][hw]
// (frozen — LDS-free, measured-good)
// ---------------------------------------------------------------------------
__global__ __launch_bounds__(256, 4) void phaseE(const unsigned short* __restrict__ mk16,
                                                 const float* __restrict__ feat,
                                                 float* __restrict__ out) {
  int tid = threadIdx.x;
  int b = blockIdx.y;
  int hw0 = blockIdx.x * 128;
  int w = tid >> 6, lane = tid & 63, quad = lane >> 4, l15 = lane & 15;
  f32x4 acc[7][2];
#pragma unroll
  for (int mt = 0; mt < 7; ++mt)
#pragma unroll
    for (int nt = 0; nt < 2; ++nt) {
      acc[mt][nt][0] = 0.f; acc[mt][nt][1] = 0.f; acc[mt][nt][2] = 0.f; acc[mt][nt][3] = 0.f;
    }
  size_t fb = (size_t)b * 256 * 16384;
  int hwl = hw0 + w * 32 + l15;
  const unsigned short* mkb_b = mk16 + (size_t)b * 100 * 256;
  for (int kk = 0; kk < 8; ++kk) {
    bfrag bv[2];
#pragma unroll
    for (int nt = 0; nt < 2; ++nt) {
#pragma unroll
      for (int j = 0; j < 8; ++j) {
        float v = feat[fb + (size_t)(kk * 32 + quad * 8 + j) * 16384 + hwl + nt * 16];
        bv[nt][j] = (short)f2bf(v);
      }
    }
    bfrag av[7];
#pragma unroll
    for (int mt = 0; mt < 7; ++mt) {
      int row = mt * 16 + l15;
      int rr = (row < 100) ? row : 0;
      av[mt] = *(const bfrag*)(mkb_b + (size_t)rr * 256 + kk * 32 + quad * 8);
    }
#pragma unroll
    for (int mt = 0; mt < 7; ++mt) {
      acc[mt][0] = __builtin_amdgcn_mfma_f32_16x16x32_bf16(av[mt], bv[0], acc[mt][0], 0, 0, 0);
      acc[mt][1] = __builtin_amdgcn_mfma_f32_16x16x32_bf16(av[mt], bv[1], acc[mt][1], 0, 0, 0);
    }
  }
#pragma unroll
  for (int mt = 0; mt < 7; ++mt)
#pragma unroll
    for (int nt = 0; nt < 2; ++nt)
#pragma unroll
      for (int r = 0; r < 4; ++r) {
        int m = mt * 16 + quad * 4 + r;
        if (m < 100)
          out[(size_t)(b * 100 + m) * 16384 + hw0 + w * 32 + nt * 16 + l15] = acc[mt][nt][r];
      }
}

// ---------------------------------------------------------------------------
extern "C" void kernel_launch(void* const* d_in, const int* in_sizes, int n_in,
                              void* d_out, int out_size, void* d_ws, size_t ws_size,
                              hipStream_t stream) {
  const float* feat    = (const float*)d_in[0];
  const float* prop    = (const float*)d_in[1];
  const float* maskp   = (const float*)d_in[2];
  const float* fW      = (const float*)d_in[3];
  const float* fb_     = (const float*)d_in[4];
  const float* fng     = (const float*)d_in[5];
  const float* fnb     = (const float*)d_in[6];
  const float* f_ng    = (const float*)d_in[7];
  const float* f_nb    = (const float*)d_in[8];
  const float* kW      = (const float*)d_in[9];
  const float* kb_     = (const float*)d_in[10];
  const float* kng     = (const float*)d_in[11];
  const float* knb     = (const float*)d_in[12];
  const float* k_ng    = (const float*)d_in[13];
  const float* k_nb    = (const float*)d_in[14];
  const float* aw_in   = (const float*)d_in[15];
  const float* ab_in   = (const float*)d_in[16];
  const float* aw_out  = (const float*)d_in[17];
  const float* ab_out  = (const float*)d_in[18];
  const float* s_ng    = (const float*)d_in[19];
  const float* s_nb    = (const float*)d_in[20];
  const float* w1      = (const float*)d_in[21];
  const float* b1      = (const float*)d_in[22];
  const float* w2      = (const float*)d_in[23];
  const float* b2      = (const float*)d_in[24];
  const float* ffn_ng  = (const float*)d_in[25];
  const float* ffn_nb  = (const float*)d_in[26];
  const float* cls_w   = (const float*)d_in[27];
  const float* cls_g   = (const float*)d_in[28];
  const float* cls_b   = (const float*)d_in[29];
  const float* fcclsw  = (const float*)d_in[30];
  const float* fcclsb  = (const float*)d_in[31];
  const float* mask_w  = (const float*)d_in[32];
  const float* mask_g  = (const float*)d_in[33];
  const float* mask_b  = (const float*)d_in[34];
  const float* fcmw    = (const float*)d_in[35];
  const float* fcmb    = (const float*)d_in[36];
  float* out = (float*)d_out;

  // ---- workspace: 32.1 MB total (proven-safe bound is 33.03 MB) ----
  float* ws = (float*)d_ws;
  size_t off = 0;
  unsigned short* wt = (unsigned short*)(ws + off); off += 681984;  // 1,363,968 bf16
  float* fm      = ws + off; off += 204800;
  float* bias_fk = ws + off; off += 208;
  unsigned int* bitsbuf = (unsigned int*)(ws + off); off += 409600;
  unsigned short* whd = (unsigned short*)(ws + off); off += 174208;  // 348,416 bf16 head W
  float* partial = ws + off;   // union region: 8*32*100*256 = 6,553,600 floats
  float* ub = partial;
  size_t uo = 0;
  float* wb   = ub + uo; uo += 166400;  // 800 x 208 fused dysep weights
  float* pt   = ub + uo; uo += 204800;
  float* fbuf = ub + uo; uo += 204800;
  float* kkb  = ub + uo; uo += 204800;
  float* qkvb = ub + uo; uo += 614400;
  float* ob   = ub + uo; uo += 204800;
  float* mo   = ub + uo; uo += 204800;
  float* kk2  = ub + uo; uo += 204800;
  float* t1   = ub + uo; uo += 819200;  // 4 k-split slabs of 800x256
  float* objb = ub + uo; uo += 204800;
  float* mkb  = ub + uo; uo += 204800;
  unsigned short* ffn1b = (unsigned short*)(ub + uo); uo += 409600;  // 800x2048 bf16
  unsigned short* mkb16 = (unsigned short*)mkb;  // 800x256 bf16 view

  // Wt sub-offsets (shorts): fW rows 0..103, kW rows 104..207 (contiguous)
  const int wt_fW = 0, wt_kW = 26624, wt_ain = 53248, wt_aout = 249856;
  const int wt_w1 = 315392, wt_w2 = 839680;

  float* out_cls  = out;                       // [800][81]
  float* out_mask = out + 64800;               // [8][100][16384]
  float* out_obj  = out + 64800 + 13107200;    // [800][256]

  // ---- weight prep ----
  Prep6 p;
  const float* srcs[6] = {fW, kW, aw_in, aw_out, w1, w2};
  int Ks[6]    = {256, 256, 256, 256, 256, 2048};
  int Ns[6]    = {103, 103, 768, 256, 2048, 256};
  int doffs[6] = {wt_fW, wt_kW, wt_ain, wt_aout, wt_w1, wt_w2};
  int tb = 0;
  for (int i = 0; i < 6; ++i) {
    p.s[i] = srcs[i]; p.K[i] = Ks[i]; p.N[i] = Ns[i]; p.doff[i] = doffs[i];
    p.base[i] = tb;
    tb += ((Ks[i] + 31) / 32) * ((Ns[i] + 31) / 32);
  }
  prep_w<<<tb, 256, 0, stream>>>(p, wt);
  prep_bias<<<1, 256, 0, stream>>>(fb_, kb_, bias_fk);
  Cast4 cc;
  const float* csrc[4] = {cls_w, fcclsw, mask_w, fcmw};
  int cn[4] = {65536, 20736, 196608, 65536};
  int cdoff[4] = {0, 65536, 86272, 282880};
  int cb = 0;
  for (int i = 0; i < 4; ++i) {
    cc.s[i] = csrc[i]; cc.n[i] = cn[i]; cc.doff[i] = cdoff[i];
    cc.base[i] = cb;
    cb += (cn[i] + 1023) / 1024;
  }
  cast_w<<<cb, 256, 0, stream>>>(cc, whd);
  pack_bits<<<12800, 256, 0, stream>>>(maskp, bitsbuf);

  // f_masked = hard(mask) @ feat^T
  phaseA<<<dim3(32, 2, 8), 512, 0, stream>>>(bitsbuf, feat, partial);
  reduceA<<<800, 256, 0, stream>>>(partial, fm);
  // fused dysep weight GEMM: [fW | kW] in one pass (N=208)
  gemm_mf<0, 0><<<dim3(13, 4, 1), 256, 0, stream>>>(prop, wt + wt_fW, bias_fk, wb, 800, 256, 208, 208, 0, 256);
  // dysep 1
  pointdw<<<dim3(8, 8), 256, 0, stream>>>(fm, wb, pt);
  ln2_kernel<<<200, 256, 0, stream>>>(pt, fm, fng, fnb, f_ng, f_nb, fbuf);
  // dysep 2
  pointdw<<<dim3(8, 8), 256, 0, stream>>>(fbuf, wb + 104, pt);
  ln2_kernel<<<200, 256, 0, stream>>>(pt, fbuf, kng, knb, k_ng, k_nb, kkb);
  // MHA
  gemm_mf<0, 0><<<dim3(13, 12, 1), 256, 0, stream>>>(kkb, wt + wt_ain, ab_in, qkvb, 800, 256, 768, 768, 0, 256);
  attn_kernel<<<dim3(32, 8), 256, 0, stream>>>(qkvb, ob);
  gemm_mf<0, 0><<<dim3(13, 4, 1), 256, 0, stream>>>(ob, wt + wt_aout, ab_out, mo, 800, 256, 256, 256, 0, 256);
  ln_kernel<<<200, 256, 0, stream>>>(mo, kkb, s_ng, s_nb, kk2, 0, nullptr);
  // FFN: ffn1 full-K; ffn2 k-split x4 into slabs, reduced in ln_ffn2
  gemm_mf<0, 1><<<dim3(13, 32, 1), 256, 0, stream>>>(kk2, wt + wt_w1, b1, ffn1b, 800, 256, 2048, 2048, 1, 256);
  gemm_mf<1, 0><<<dim3(13, 4, 4), 256, 0, stream>>>(ffn1b, wt + wt_w2, nullptr, t1, 800, 2048, 256, 256, 0, 512);
  ln_ffn2<<<200, 256, 0, stream>>>(t1, b2, kk2, ffn_ng, ffn_nb, objb, out_obj);
  // fused cls + mask head
  head_fused<<<800, 256, 0, stream>>>(objb, whd, cls_g, cls_b, fcclsb,
                                      mask_g, mask_b, fcmb, out_cls, mkb16);
  // new_mask_preds = mk @ feat
  phaseE<<<dim3(128, 8), 256, 0, stream>>>(mkb16, feat, out_mask);
}

// Round 6
// 556.831 us; speedup vs baseline: 1.5224x; 1.0560x over previous
//
#include <hip/hip_runtime.h>

typedef float f32x4 __attribute__((ext_vector_type(4)));
typedef short bfrag __attribute__((ext_vector_type(8)));
typedef short sh4 __attribute__((ext_vector_type(4)));

__device__ __forceinline__ unsigned short f2bf(float x) {
  unsigned int u = __float_as_uint(x);
  return (unsigned short)((u + 0x7FFFu + ((u >> 16) & 1u)) >> 16);
}
__device__ __forceinline__ float bf2f(unsigned short u) {
  return __uint_as_float(((unsigned int)u) << 16);
}
__device__ __forceinline__ float wred_sum(float v) {
#pragma unroll
  for (int o = 32; o > 0; o >>= 1) v += __shfl_xor(v, o);
  return v;
}
__device__ __forceinline__ float wred_max(float v) {
#pragma unroll
  for (int o = 32; o > 0; o >>= 1) v = fmaxf(v, __shfl_xor(v, o));
  return v;
}

// ---------------------------------------------------------------------------
// Weight prep: Wt[n][k] (bf16, k-contiguous) = W[k][n].
// fW at rows 0..103, kW at rows 104..207 (both pw/dw col-permuted).
// ---------------------------------------------------------------------------
struct Prep6 {
  const float* s[6];
  int K[6];
  int N[6];
  int base[6];
  int doff[6];
};

__global__ __launch_bounds__(256) void prep_w(Prep6 p, unsigned short* wt) {
  int t = blockIdx.x;
  int wi = 0;
#pragma unroll
  for (int i = 0; i < 5; ++i)
    if (t >= p.base[i + 1]) wi = i + 1;
  int lt = t - p.base[wi];
  int K = p.K[wi], N = p.N[wi];
  int tkn = (K + 31) >> 5;
  int tk = lt % tkn, tn = lt / tkn;
  __shared__ float tile[32][33];
  const float* src = p.s[wi];
#pragma unroll
  for (int i = 0; i < 4; ++i) {
    int flat = i * 256 + threadIdx.x;
    int kl = flat >> 5, nl = flat & 31;
    int k = tk * 32 + kl, n = tn * 32 + nl;
    tile[kl][nl] = (k < K && n < N) ? src[(size_t)k * N + n] : 0.f;
  }
  __syncthreads();
  unsigned short* dst = wt + p.doff[wi];
#pragma unroll
  for (int i = 0; i < 4; ++i) {
    int flat = i * 256 + threadIdx.x;
    int nl = flat >> 5, kl = flat & 31;
    int k = tk * 32 + kl, n = tn * 32 + nl;
    if (k < K && n < N) {
      int np = (wi < 2) ? ((n >= 3) ? n - 3 : n + 100) : n;
      dst[(size_t)np * K + k] = f2bf(tile[kl][nl]);
    }
  }
}

// bias_fk[208]: [0..103] = fb permuted, [104..207] = kb permuted
__global__ __launch_bounds__(256) void prep_bias(const float* __restrict__ fb_,
                                                 const float* __restrict__ kb_,
                                                 float* __restrict__ bfk) {
  int t = threadIdx.x;
  if (t < 103) {
    int np = (t >= 3) ? t - 3 : t + 100;
    bfk[np] = fb_[t];
    bfk[104 + np] = kb_[t];
  }
  if (t == 103) { bfk[103] = 0.f; bfk[207] = 0.f; }
}

// ---------------------------------------------------------------------------
// cast_w: head weights f32 -> bf16, original [k][n] layout (no transpose).
// ---------------------------------------------------------------------------
struct Cast4 {
  const float* s[4];
  int n[4];
  int base[4];
  int doff[4];
};

__global__ __launch_bounds__(256) void cast_w(Cast4 cc, unsigned short* dst) {
  int t = blockIdx.x;
  int wi = 0;
#pragma unroll
  for (int i = 0; i < 3; ++i)
    if (t >= cc.base[i + 1]) wi = i + 1;
  int lt = t - cc.base[wi];
  int idx = lt * 1024 + threadIdx.x * 4;
  if (idx + 3 < cc.n[wi]) {
    float4 v = *(const float4*)(cc.s[wi] + idx);
    sh4 o;
    o[0] = (short)f2bf(v.x); o[1] = (short)f2bf(v.y);
    o[2] = (short)f2bf(v.z); o[3] = (short)f2bf(v.w);
    *(sh4*)(dst + cc.doff[wi] + idx) = o;
  }
}

// ---------------------------------------------------------------------------
// pack_bits: hard mask (mask>0) packed 1 bit/elem.
// ---------------------------------------------------------------------------
__global__ __launch_bounds__(256) void pack_bits(const float* __restrict__ mask,
                                                 unsigned int* __restrict__ bits) {
  int tid = threadIdx.x;
  size_t f = (size_t)blockIdx.x * 256 + tid;
  float4 m = *(const float4*)(mask + f * 4);
  unsigned int n = (m.x > 0.f ? 1u : 0u) | (m.y > 0.f ? 2u : 0u) |
                   (m.z > 0.f ? 4u : 0u) | (m.w > 0.f ? 8u : 0u);
  n <<= ((tid & 7) * 4);
  n |= (unsigned int)__shfl_xor((int)n, 1);
  n |= (unsigned int)__shfl_xor((int)n, 2);
  n |= (unsigned int)__shfl_xor((int)n, 4);
  if ((tid & 7) == 0) bits[((size_t)blockIdx.x * 32) + (tid >> 3)] = n;
}

// ---------------------------------------------------------------------------
// MFMA GEMM with K-slab support (blockIdx.z): see v5 notes.
// ---------------------------------------------------------------------------
template <int ABF, int OBF>
__global__ __launch_bounds__(256) void gemm_mf(const void* Av,
                                               const unsigned short* __restrict__ Wt,
                                               const float* __restrict__ bias,
                                               void* Cv, int M, int K, int N, int ldc, int relu,
                                               int kspan) {
  __shared__ short Al[64 * 72];
  __shared__ short Wl[64 * 72];
  int tid = threadIdx.x;
  int r0 = blockIdx.x * 64;
  int c0 = blockIdx.y * 64;
  int kz = blockIdx.z * kspan;
  int w = tid >> 6, lane = tid & 63, quad = lane >> 4, l15 = lane & 15;

  f32x4 acc[4];
#pragma unroll
  for (int mt = 0; mt < 4; ++mt) {
    acc[mt][0] = 0.f; acc[mt][1] = 0.f; acc[mt][2] = 0.f; acc[mt][3] = 0.f;
  }

  for (int k0 = kz; k0 < kz + kspan; k0 += 64) {
    if (ABF) {
      const unsigned short* A = (const unsigned short*)Av;
#pragma unroll
      for (int p = 0; p < 2; ++p) {
        int flat = p * 256 + tid;
        int row = flat >> 3, k8 = flat & 7;
        bfrag v;
        if (r0 + row < M)
          v = *(const bfrag*)(A + (size_t)(r0 + row) * K + k0 + k8 * 8);
        else
          v = (bfrag)(short)0;
        *(bfrag*)(Al + row * 72 + k8 * 8) = v;
      }
    } else {
      const float* A = (const float*)Av;
#pragma unroll
      for (int p = 0; p < 4; ++p) {
        int flat = p * 256 + tid;
        int row = flat >> 4, c4 = flat & 15;
        sh4 o4;
        if (r0 + row < M) {
          float4 v = *(const float4*)(A + (size_t)(r0 + row) * K + k0 + c4 * 4);
          o4[0] = (short)f2bf(v.x); o4[1] = (short)f2bf(v.y);
          o4[2] = (short)f2bf(v.z); o4[3] = (short)f2bf(v.w);
        } else {
          o4[0] = 0; o4[1] = 0; o4[2] = 0; o4[3] = 0;
        }
        *(sh4*)(Al + row * 72 + c4 * 4) = o4;
      }
    }
#pragma unroll
    for (int p = 0; p < 2; ++p) {
      int flat = p * 256 + tid;
      int row = flat >> 3, k8 = flat & 7;
      bfrag v;
      if (c0 + row < N)
        v = *(const bfrag*)(Wt + (size_t)(c0 + row) * K + k0 + k8 * 8);
      else
        v = (bfrag)(short)0;
      *(bfrag*)(Wl + row * 72 + k8 * 8) = v;
    }
    __syncthreads();
#pragma unroll
    for (int kk = 0; kk < 2; ++kk) {
      bfrag bv = *(const bfrag*)(Wl + (w * 16 + l15) * 72 + kk * 32 + quad * 8);
#pragma unroll
      for (int mt = 0; mt < 4; ++mt) {
        bfrag av = *(const bfrag*)(Al + (mt * 16 + l15) * 72 + kk * 32 + quad * 8);
        acc[mt] = __builtin_amdgcn_mfma_f32_16x16x32_bf16(av, bv, acc[mt], 0, 0, 0);
      }
    }
    __syncthreads();
  }
  int col = c0 + w * 16 + l15;
  if (col < N) {
    float bv = bias ? bias[col] : 0.f;
    size_t zoff = (size_t)blockIdx.z * M * ldc;
#pragma unroll
    for (int mt = 0; mt < 4; ++mt)
#pragma unroll
      for (int r = 0; r < 4; ++r) {
        int m = r0 + mt * 16 + quad * 4 + r;
        if (m < M) {
          float v = acc[mt][r] + bv;
          if (relu) v = fmaxf(v, 0.f);
          if (OBF)
            ((unsigned short*)Cv)[zoff + (size_t)m * ldc + col] = f2bf(v);
          else
            ((float*)Cv)[zoff + (size_t)m * ldc + col] = v;
        }
      }
  }
}

// ---------------------------------------------------------------------------
// Phase A v6: concurrency experiment done right. 256-thread blocks, ct 0..3
// (64 feat rows each) -> grid 1024 blocks; single LDS buffer 25.3 KB ->
// ~6 resident blocks/CU (24 waves/CU) vs v5's 2 blocks/CU. Same total traffic
// (feat read exactly once; bits read 4x, L2-resident).
// ---------------------------------------------------------------------------
__global__ __launch_bounds__(256, 6) void phaseA(const unsigned int* __restrict__ bits,
                                                 const float* __restrict__ feat,
                                                 float* __restrict__ partial) {
  int tid = threadIdx.x;
  int ks = blockIdx.x;  // 0..31
  int ct = blockIdx.y;  // 0..3
  int b  = blockIdx.z;  // 0..7
  __shared__ short Al[112 * 72];
  __shared__ short Bl[64 * 72];
  int w = tid >> 6, lane = tid & 63, quad = lane >> 4, l15 = lane & 15;

  // B staging: row = tid>>2 (0..63), s = tid&3; 4 float4 at float4-idx 4i+s
  int brow = tid >> 2, s = tid & 3;
  const float* frow = feat + (size_t)(b * 256 + ct * 64 + brow) * 16384 + s * 4;

  // A staging: threads 0..199: arow = tid>>1, half = tid&1 (one 32-bit word)
  int arow = tid >> 1, half = tid & 1;
  bool aact = tid < 200;
  const unsigned int* browb = bits + (size_t)(b * 100 + arow) * 512 + half;

  f32x4 acc[7];
#pragma unroll
  for (int mt = 0; mt < 7; ++mt) {
    acc[mt][0] = 0.f; acc[mt][1] = 0.f; acc[mt][2] = 0.f; acc[mt][3] = 0.f;
  }

  // zero A pad rows 100..111 once (12 rows x 18 sh4)
  for (int z = tid; z < 216; z += 256) {
    sh4 zz; zz[0] = 0; zz[1] = 0; zz[2] = 0; zz[3] = 0;
    *(sh4*)(&Al[(100 + z / 18) * 72 + (z % 18) * 4]) = zz;
  }

  int k0 = ks * 512;
  for (int st = 0; st < 8; ++st) {
    int kb = k0 + st * 64;
    float4 bpf[4];
#pragma unroll
    for (int i = 0; i < 4; ++i)
      bpf[i] = *(const float4*)(frow + kb + i * 16);
    unsigned int awd = aact ? browb[kb >> 5] : 0u;
    __syncthreads();  // prior MFMA reads complete before overwrite
#pragma unroll
    for (int i = 0; i < 4; ++i) {
      sh4 o4;
      o4[0] = (short)f2bf(bpf[i].x);
      o4[1] = (short)f2bf(bpf[i].y);
      o4[2] = (short)f2bf(bpf[i].z);
      o4[3] = (short)f2bf(bpf[i].w);
      *(sh4*)(&Bl[brow * 72 + i * 16 + s * 4]) = o4;
    }
    if (aact) {
#pragma unroll
      for (int j = 0; j < 4; ++j) {
        bfrag e;
#pragma unroll
        for (int i2 = 0; i2 < 8; ++i2)
          e[i2] = ((awd >> (j * 8 + i2)) & 1u) ? (short)0x3F80 : (short)0;
        *(bfrag*)(&Al[arow * 72 + half * 32 + j * 8]) = e;
      }
    }
    __syncthreads();
#pragma unroll
    for (int kk = 0; kk < 2; ++kk) {
      bfrag bv = *(const bfrag*)(&Bl[(w * 16 + l15) * 72 + kk * 32 + quad * 8]);
#pragma unroll
      for (int mt = 0; mt < 7; ++mt) {
        bfrag av = *(const bfrag*)(&Al[(mt * 16 + l15) * 72 + kk * 32 + quad * 8]);
        acc[mt] = __builtin_amdgcn_mfma_f32_16x16x32_bf16(av, bv, acc[mt], 0, 0, 0);
      }
    }
  }

  float* pb = partial + (size_t)(b * 32 + ks) * (100 * 256) + ct * 64 + w * 16 + l15;
#pragma unroll
  for (int mt = 0; mt < 7; ++mt)
#pragma unroll
    for (int r = 0; r < 4; ++r) {
      int m = mt * 16 + quad * 4 + r;
      if (m < 100) pb[(size_t)m * 256] = acc[mt][r];
    }
}

__global__ __launch_bounds__(256) void reduceA(const float* __restrict__ partial,
                                               float* __restrict__ fm) {
  int gid = blockIdx.x * 256 + threadIdx.x;
  int c = gid & 255, row = gid >> 8;
  int b = row / 100, n = row % 100;
  float s = 0.f;
#pragma unroll
  for (int ks = 0; ks < 32; ++ks)
    s += partial[((size_t)(b * 32 + ks) * 100 + n) * 256 + c];
  fm[(size_t)row * 256 + c] = s;
}

// ---------------------------------------------------------------------------
// dysep middle v2: 16-col chunks -> grid (16,8)=128 blocks (2x parallelism,
// half the serial m-iterations). wbuf rows stride 208.
// ---------------------------------------------------------------------------
__global__ __launch_bounds__(256) void pointdw(const float* __restrict__ fm,
                                               const float* __restrict__ wbuf,
                                               float* __restrict__ point) {
  int tid = threadIdx.x;
  int b = blockIdx.y, c0 = blockIdx.x * 16;
  __shared__ float dl[100 * 17];
  for (int flat = tid; flat < 1600; flat += 256) {
    int n = flat >> 4, cl = flat & 15, c = c0 + cl;
    const float* fr = fm + (size_t)(b * 100 + n) * 256;
    const float* wr = wbuf + (size_t)(b * 100 + n) * 208;
    float x0 = (c > 0) ? fr[c - 1] : 0.f;
    float x1 = fr[c];
    float x2 = (c < 255) ? fr[c + 1] : 0.f;
    float d = wr[100] * x0 + wr[101] * x1 + wr[102] * x2;
    dl[n * 17 + cl] = fmaxf(d, 0.f);
  }
  __syncthreads();
  int cl = tid & 15, mg = tid >> 4;
  for (int m = mg; m < 100; m += 16) {
    const float4* pw4 = (const float4*)(wbuf + (size_t)(b * 100 + m) * 208);
    float a = 0.f;
#pragma unroll
    for (int n4 = 0; n4 < 25; ++n4) {
      float4 wv = pw4[n4];
      a += wv.x * dl[(n4 * 4 + 0) * 17 + cl] + wv.y * dl[(n4 * 4 + 1) * 17 + cl]
         + wv.z * dl[(n4 * 4 + 2) * 17 + cl] + wv.w * dl[(n4 * 4 + 3) * 17 + cl];
    }
    point[(size_t)(b * 100 + m) * 256 + c0 + cl] = a;
  }
}

// ---------------------------------------------------------------------------
__global__ __launch_bounds__(256) void ln2_kernel(const float* __restrict__ x,
                                                  const float* __restrict__ resid,
                                                  const float* __restrict__ g1, const float* __restrict__ b1,
                                                  const float* __restrict__ g2, const float* __restrict__ b2,
                                                  float* __restrict__ out) {
  int tid = threadIdx.x;
  int row = blockIdx.x * 4 + (tid >> 6);
  int lane = tid & 63;
  size_t base = (size_t)row * 256 + lane * 4;
  float4 v = *(const float4*)(x + base);
  float mean = wred_sum(v.x + v.y + v.z + v.w) * (1.f / 256.f);
  float d0 = v.x - mean, d1 = v.y - mean, d2 = v.z - mean, d3 = v.w - mean;
  float rs = rsqrtf(wred_sum(d0 * d0 + d1 * d1 + d2 * d2 + d3 * d3) * (1.f / 256.f) + 1e-5f);
  float4 gv = *(const float4*)(g1 + lane * 4);
  float4 bv = *(const float4*)(b1 + lane * 4);
  float4 rv = *(const float4*)(resid + base);
  float y0 = rv.x + d0 * rs * gv.x + bv.x;
  float y1 = rv.y + d1 * rs * gv.y + bv.y;
  float y2 = rv.z + d2 * rs * gv.z + bv.z;
  float y3 = rv.w + d3 * rs * gv.w + bv.w;
  float mean2 = wred_sum(y0 + y1 + y2 + y3) * (1.f / 256.f);
  float e0 = y0 - mean2, e1 = y1 - mean2, e2 = y2 - mean2, e3 = y3 - mean2;
  float rs2 = rsqrtf(wred_sum(e0 * e0 + e1 * e1 + e2 * e2 + e3 * e3) * (1.f / 256.f) + 1e-5f);
  float4 g2v = *(const float4*)(g2 + lane * 4);
  float4 b2v = *(const float4*)(b2 + lane * 4);
  float4 o;
  o.x = e0 * rs2 * g2v.x + b2v.x;
  o.y = e1 * rs2 * g2v.y + b2v.y;
  o.z = e2 * rs2 * g2v.z + b2v.z;
  o.w = e3 * rs2 * g2v.w + b2v.w;
  *(float4*)(out + base) = o;
}

__global__ __launch_bounds__(256) void ln_kernel(const float* __restrict__ x,
                                                 const float* __restrict__ res,
                                                 const float* __restrict__ g, const float* __restrict__ bb,
                                                 float* __restrict__ out, int relu,
                                                 float* __restrict__ copy2) {
  int tid = threadIdx.x;
  int row = blockIdx.x * 4 + (tid >> 6);
  int lane = tid & 63;
  size_t base = (size_t)row * 256 + lane * 4;
  float4 v = *(const float4*)(x + base);
  if (res) {
    float4 rv = *(const float4*)(res + base);
    v.x += rv.x; v.y += rv.y; v.z += rv.z; v.w += rv.w;
  }
  float mean = wred_sum(v.x + v.y + v.z + v.w) * (1.f / 256.f);
  float d0 = v.x - mean, d1 = v.y - mean, d2 = v.z - mean, d3 = v.w - mean;
  float rs = rsqrtf(wred_sum(d0 * d0 + d1 * d1 + d2 * d2 + d3 * d3) * (1.f / 256.f) + 1e-5f);
  float4 gv = *(const float4*)(g + lane * 4);
  float4 bv = *(const float4*)(bb + lane * 4);
  float4 o;
  o.x = d0 * rs * gv.x + bv.x;
  o.y = d1 * rs * gv.y + bv.y;
  o.z = d2 * rs * gv.z + bv.z;
  o.w = d3 * rs * gv.w + bv.w;
  if (relu) {
    o.x = fmaxf(o.x, 0.f); o.y = fmaxf(o.y, 0.f);
    o.z = fmaxf(o.z, 0.f); o.w = fmaxf(o.w, 0.f);
  }
  *(float4*)(out + base) = o;
  if (copy2) *(float4*)(copy2 + base) = o;
}

// ---------------------------------------------------------------------------
// ln_ffn2: v = sum of 4 k-split GEMM slabs + b2 + residual -> LN -> out (+copy)
// ---------------------------------------------------------------------------
__global__ __launch_bounds__(256) void ln_ffn2(const float* __restrict__ t1,
                                               const float* __restrict__ b2,
                                               const float* __restrict__ res,
                                               const float* __restrict__ g, const float* __restrict__ bb,
                                               float* __restrict__ out,
                                               float* __restrict__ copy2) {
  int tid = threadIdx.x;
  int row = blockIdx.x * 4 + (tid >> 6);
  int lane = tid & 63;
  size_t base = (size_t)row * 256 + lane * 4;
  float4 v = *(const float4*)(t1 + base);
#pragma unroll
  for (int s = 1; s < 4; ++s) {
    float4 p = *(const float4*)(t1 + (size_t)s * 204800 + base);
    v.x += p.x; v.y += p.y; v.z += p.z; v.w += p.w;
  }
  float4 b2v = *(const float4*)(b2 + lane * 4);
  float4 rv = *(const float4*)(res + base);
  v.x += b2v.x + rv.x; v.y += b2v.y + rv.y; v.z += b2v.z + rv.z; v.w += b2v.w + rv.w;
  float mean = wred_sum(v.x + v.y + v.z + v.w) * (1.f / 256.f);
  float d0 = v.x - mean, d1 = v.y - mean, d2 = v.z - mean, d3 = v.w - mean;
  float rs = rsqrtf(wred_sum(d0 * d0 + d1 * d1 + d2 * d2 + d3 * d3) * (1.f / 256.f) + 1e-5f);
  float4 gv = *(const float4*)(g + lane * 4);
  float4 bv = *(const float4*)(bb + lane * 4);
  float4 o;
  o.x = d0 * rs * gv.x + bv.x;
  o.y = d1 * rs * gv.y + bv.y;
  o.z = d2 * rs * gv.z + bv.z;
  o.w = d3 * rs * gv.w + bv.w;
  *(float4*)(out + base) = o;
  *(float4*)(copy2 + base) = o;
}

// ---------------------------------------------------------------------------
// MHA: one block per (head, batch, q-quarter). 256 blocks. (frozen)
// ---------------------------------------------------------------------------
__global__ __launch_bounds__(256) void attn_kernel(const float* __restrict__ qkv,
                                                   float* __restrict__ obuf) {
  int tid = threadIdx.x;
  int b = blockIdx.y, h = blockIdx.x & 7, qq = blockIdx.x >> 3;
  __shared__ float ktj[100 * 32];          // k [j][dd]
  __shared__ unsigned short vl[100 * 32];  // v bf16 [j][dd]
  __shared__ float sl[25 * 100];
  const float* base = qkv + (size_t)b * 100 * 768;
  for (int flat = tid; flat < 3200; flat += 256) {
    int j = flat >> 5, dd = flat & 31;
    ktj[j * 32 + dd] = base[(size_t)j * 768 + 256 + h * 32 + dd];
    vl[j * 32 + dd] = f2bf(base[(size_t)j * 768 + 512 + h * 32 + dd]);
  }
  __syncthreads();
  {
    int il = tid % 25;
    int jseg = tid / 25;
    int i = qq * 25 + il;
    const float4* q4 = (const float4*)(base + (size_t)i * 768 + h * 32);
    float4 q[8];
#pragma unroll
    for (int d4 = 0; d4 < 8; ++d4) q[d4] = q4[d4];
    if (jseg < 10) {
      for (int jj = 0; jj < 10; ++jj) {
        int j = jseg * 10 + jj;
        const float4* kr = (const float4*)(ktj + j * 32);
        float a = 0.f;
#pragma unroll
        for (int d4 = 0; d4 < 8; ++d4) {
          float4 kv = kr[d4];
          a += q[d4].x * kv.x + q[d4].y * kv.y + q[d4].z * kv.z + q[d4].w * kv.w;
        }
        sl[il * 100 + j] = a * 0.17677669529663687f;
      }
    }
  }
  __syncthreads();
  int w = tid >> 6, lane = tid & 63;
  for (int r = w; r < 25; r += 4) {
    float x0 = sl[r * 100 + lane];
    float x1 = (lane + 64 < 100) ? sl[r * 100 + lane + 64] : -1e30f;
    float mx = wred_max(fmaxf(x0, x1));
    float e0 = __expf(x0 - mx);
    float e1 = (lane + 64 < 100) ? __expf(x1 - mx) : 0.f;
    float inv = 1.f / wred_sum(e0 + e1);
    sl[r * 100 + lane] = e0 * inv;
    if (lane + 64 < 100) sl[r * 100 + lane + 64] = e1 * inv;
  }
  __syncthreads();
  for (int flat = tid; flat < 800; flat += 256) {
    int il = flat >> 5, dd = flat & 31;
    float a = 0.f;
#pragma unroll 4
    for (int j = 0; j < 100; ++j) a += sl[il * 100 + j] * bf2f(vl[j * 32 + dd]);
    obuf[(size_t)(b * 100 + qq * 25 + il) * 256 + h * 32 + dd] = a;
  }
}

// ---------------------------------------------------------------------------
// Fused cls + mask head: one row per block (800 blocks, 4 waves, k-split).
// (frozen)
// ---------------------------------------------------------------------------
__global__ __launch_bounds__(256) void head_fused(
    const float* __restrict__ objb,
    const unsigned short* __restrict__ whd,
    const float* __restrict__ cls_g, const float* __restrict__ cls_b,
    const float* __restrict__ fcclsb,
    const float* __restrict__ mask_g, const float* __restrict__ mask_b,
    const float* __restrict__ fcmb,
    float* __restrict__ out_cls, unsigned short* __restrict__ mk16) {
  const int WH_CLS = 0, WH_FCCLS = 65536, WH_M = 86272, WH_FCM = 282880;
  int tid = threadIdx.x, wv = tid >> 6, lane = tid & 63;
  int row = blockIdx.x;
  __shared__ float xs[256];
  __shared__ float x0s[256];
  __shared__ float ps[4][256];
  if (wv == 0) {
    float4 v = *(const float4*)(objb + (size_t)row * 256 + lane * 4);
    *(float4*)(&xs[lane * 4]) = v;
    *(float4*)(&x0s[lane * 4]) = v;
  }
  __syncthreads();
  int c = lane * 4;
  int kb = wv * 64;

  for (int li = 0; li < 3; ++li) {
    const unsigned short* W = whd + WH_M + li * 65536;
    float a0 = 0.f, a1 = 0.f, a2 = 0.f, a3 = 0.f;
#pragma unroll 8
    for (int k = kb; k < kb + 64; ++k) {
      float xk = xs[k];
      sh4 w4 = *(const sh4*)(W + (size_t)k * 256 + c);
      a0 += xk * bf2f((unsigned short)w4[0]);
      a1 += xk * bf2f((unsigned short)w4[1]);
      a2 += xk * bf2f((unsigned short)w4[2]);
      a3 += xk * bf2f((unsigned short)w4[3]);
    }
    ps[wv][c] = a0; ps[wv][c + 1] = a1; ps[wv][c + 2] = a2; ps[wv][c + 3] = a3;
    __syncthreads();
    float s0 = ps[0][c] + ps[1][c] + ps[2][c] + ps[3][c];
    float s1 = ps[0][c + 1] + ps[1][c + 1] + ps[2][c + 1] + ps[3][c + 1];
    float s2 = ps[0][c + 2] + ps[1][c + 2] + ps[2][c + 2] + ps[3][c + 2];
    float s3 = ps[0][c + 3] + ps[1][c + 3] + ps[2][c + 3] + ps[3][c + 3];
    float mean = wred_sum(s0 + s1 + s2 + s3) * (1.f / 256.f);
    float d0 = s0 - mean, d1 = s1 - mean, d2 = s2 - mean, d3 = s3 - mean;
    float rs = rsqrtf(wred_sum(d0 * d0 + d1 * d1 + d2 * d2 + d3 * d3) * (1.f / 256.f) + 1e-5f);
    float4 gv = *(const float4*)(mask_g + li * 256 + c);
    float4 bv = *(const float4*)(mask_b + li * 256 + c);
    float4 o;
    o.x = fmaxf(d0 * rs * gv.x + bv.x, 0.f);
    o.y = fmaxf(d1 * rs * gv.y + bv.y, 0.f);
    o.z = fmaxf(d2 * rs * gv.z + bv.z, 0.f);
    o.w = fmaxf(d3 * rs * gv.w + bv.w, 0.f);
    __syncthreads();
    *(float4*)(&xs[c]) = o;
    __syncthreads();
  }
  {
    const unsigned short* W = whd + WH_FCM;
    float a0 = 0.f, a1 = 0.f, a2 = 0.f, a3 = 0.f;
#pragma unroll 8
    for (int k = kb; k < kb + 64; ++k) {
      float xk = xs[k];
      sh4 w4 = *(const sh4*)(W + (size_t)k * 256 + c);
      a0 += xk * bf2f((unsigned short)w4[0]);
      a1 += xk * bf2f((unsigned short)w4[1]);
      a2 += xk * bf2f((unsigned short)w4[2]);
      a3 += xk * bf2f((unsigned short)w4[3]);
    }
    ps[wv][c] = a0; ps[wv][c + 1] = a1; ps[wv][c + 2] = a2; ps[wv][c + 3] = a3;
    __syncthreads();
    if (wv == 0) {
      float s0 = ps[0][c] + ps[1][c] + ps[2][c] + ps[3][c];
      float s1 = ps[0][c + 1] + ps[1][c + 1] + ps[2][c + 1] + ps[3][c + 1];
      float s2 = ps[0][c + 2] + ps[1][c + 2] + ps[2][c + 2] + ps[3][c + 2];
      float s3 = ps[0][c + 3] + ps[1][c + 3] + ps[2][c + 3] + ps[3][c + 3];
      float4 bv = *(const float4*)(fcmb + c);
      sh4 o;
      o[0] = (short)f2bf(s0 + bv.x); o[1] = (short)f2bf(s1 + bv.y);
      o[2] = (short)f2bf(s2 + bv.z); o[3] = (short)f2bf(s3 + bv.w);
      *(sh4*)(mk16 + (size_t)row * 256 + c) = o;
    }
    __syncthreads();
  }
  {
    const unsigned short* W = whd + WH_CLS;
    float a0 = 0.f, a1 = 0.f, a2 = 0.f, a3 = 0.f;
#pragma unroll 8
    for (int k = kb; k < kb + 64; ++k) {
      float xk = x0s[k];
      sh4 w4 = *(const sh4*)(W + (size_t)k * 256 + c);
      a0 += xk * bf2f((unsigned short)w4[0]);
      a1 += xk * bf2f((unsigned short)w4[1]);
      a2 += xk * bf2f((unsigned short)w4[2]);
      a3 += xk * bf2f((unsigned short)w4[3]);
    }
    ps[wv][c] = a0; ps[wv][c + 1] = a1; ps[wv][c + 2] = a2; ps[wv][c + 3] = a3;
    __syncthreads();
    float s0 = ps[0][c] + ps[1][c] + ps[2][c] + ps[3][c];
    float s1 = ps[0][c + 1] + ps[1][c + 1] + ps[2][c + 1] + ps[3][c + 1];
    float s2 = ps[0][c + 2] + ps[1][c + 2] + ps[2][c + 2] + ps[3][c + 2];
    float s3 = ps[0][c + 3] + ps[1][c + 3] + ps[2][c + 3] + ps[3][c + 3];
    float mean = wred_sum(s0 + s1 + s2 + s3) * (1.f / 256.f);
    float d0 = s0 - mean, d1 = s1 - mean, d2 = s2 - mean, d3 = s3 - mean;
    float rs = rsqrtf(wred_sum(d0 * d0 + d1 * d1 + d2 * d2 + d3 * d3) * (1.f / 256.f) + 1e-5f);
    float4 gv = *(const float4*)(cls_g + c);
    float4 bv = *(const float4*)(cls_b + c);
    float4 o;
    o.x = fmaxf(d0 * rs * gv.x + bv.x, 0.f);
    o.y = fmaxf(d1 * rs * gv.y + bv.y, 0.f);
    o.z = fmaxf(d2 * rs * gv.z + bv.z, 0.f);
    o.w = fmaxf(d3 * rs * gv.w + bv.w, 0.f);
    __syncthreads();
    *(float4*)(&xs[c]) = o;
    __syncthreads();
  }
  {
    const unsigned short* W = whd + WH_FCCLS;
    float a0 = 0.f, a1 = 0.f;
#pragma unroll 8
    for (int k = kb; k < kb + 64; ++k) {
      float xk = xs[k];
      a0 += xk * bf2f(W[(size_t)k * 81 + lane]);
      if (lane < 17) a1 += xk * bf2f(W[(size_t)k * 81 + 64 + lane]);
    }
    ps[wv][lane] = a0;
    if (lane < 17) ps[wv][64 + lane] = a1;
    __syncthreads();
    if (wv == 0) {
      float s = ps[0][lane] + ps[1][lane] + ps[2][lane] + ps[3][lane];
      out_cls[(size_t)row * 81 + lane] = s + fcclsb[lane];
      if (lane < 17) {
        float s2 = ps[0][64 + lane] + ps[1][64 + lane] + ps[2][64 + lane] + ps[3][64 + lane];
        out_cls[(size_t)row * 81 + 64 + lane] = s2 + fcclsb[64 + lane];
      }
    }
  }
}

// ---------------------------------------------------------------------------
// Phase E: out[b][q][hw] = sum_c mk[b][q][c] * feat[b][c][hw] (frozen)
// ---------------------------------------------------------------------------
__global__ __launch_bounds__(256, 4) void phaseE(const unsigned short* __restrict__ mk16,
                                                 const float* __restrict__ feat,
                                                 float* __restrict__ out) {
  int tid = threadIdx.x;
  int b = blockIdx.y;
  int hw0 = blockIdx.x * 128;
  int w = tid >> 6, lane = tid & 63, quad = lane >> 4, l15 = lane & 15;
  f32x4 acc[7][2];
#pragma unroll
  for (int mt = 0; mt < 7; ++mt)
#pragma unroll
    for (int nt = 0; nt < 2; ++nt) {
      acc[mt][nt][0] = 0.f; acc[mt][nt][1] = 0.f; acc[mt][nt][2] = 0.f; acc[mt][nt][3] = 0.f;
    }
  size_t fb = (size_t)b * 256 * 16384;
  int hwl = hw0 + w * 32 + l15;
  const unsigned short* mkb_b = mk16 + (size_t)b * 100 * 256;
  for (int kk = 0; kk < 8; ++kk) {
    bfrag bv[2];
#pragma unroll
    for (int nt = 0; nt < 2; ++nt) {
#pragma unroll
      for (int j = 0; j < 8; ++j) {
        float v = feat[fb + (size_t)(kk * 32 + quad * 8 + j) * 16384 + hwl + nt * 16];
        bv[nt][j] = (short)f2bf(v);
      }
    }
    bfrag av[7];
#pragma unroll
    for (int mt = 0; mt < 7; ++mt) {
      int row = mt * 16 + l15;
      int rr = (row < 100) ? row : 0;
      av[mt] = *(const bfrag*)(mkb_b + (size_t)rr * 256 + kk * 32 + quad * 8);
    }
#pragma unroll
    for (int mt = 0; mt < 7; ++mt) {
      acc[mt][0] = __builtin_amdgcn_mfma_f32_16x16x32_bf16(av[mt], bv[0], acc[mt][0], 0, 0, 0);
      acc[mt][1] = __builtin_amdgcn_mfma_f32_16x16x32_bf16(av[mt], bv[1], acc[mt][1], 0, 0, 0);
    }
  }
#pragma unroll
  for (int mt = 0; mt < 7; ++mt)
#pragma unroll
    for (int nt = 0; nt < 2; ++nt)
#pragma unroll
      for (int r = 0; r < 4; ++r) {
        int m = mt * 16 + quad * 4 + r;
        if (m < 100)
          out[(size_t)(b * 100 + m) * 16384 + hw0 + w * 32 + nt * 16 + l15] = acc[mt][nt][r];
      }
}

// ---------------------------------------------------------------------------
extern "C" void kernel_launch(void* const* d_in, const int* in_sizes, int n_in,
                              void* d_out, int out_size, void* d_ws, size_t ws_size,
                              hipStream_t stream) {
  const float* feat    = (const float*)d_in[0];
  const float* prop    = (const float*)d_in[1];
  const float* maskp   = (const float*)d_in[2];
  const float* fW      = (const float*)d_in[3];
  const float* fb_     = (const float*)d_in[4];
  const float* fng     = (const float*)d_in[5];
  const float* fnb     = (const float*)d_in[6];
  const float* f_ng    = (const float*)d_in[7];
  const float* f_nb    = (const float*)d_in[8];
  const float* kW      = (const float*)d_in[9];
  const float* kb_     = (const float*)d_in[10];
  const float* kng     = (const float*)d_in[11];
  const float* knb     = (const float*)d_in[12];
  const float* k_ng    = (const float*)d_in[13];
  const float* k_nb    = (const float*)d_in[14];
  const float* aw_in   = (const float*)d_in[15];
  const float* ab_in   = (const float*)d_in[16];
  const float* aw_out  = (const float*)d_in[17];
  const float* ab_out  = (const float*)d_in[18];
  const float* s_ng    = (const float*)d_in[19];
  const float* s_nb    = (const float*)d_in[20];
  const float* w1      = (const float*)d_in[21];
  const float* b1      = (const float*)d_in[22];
  const float* w2      = (const float*)d_in[23];
  const float* b2      = (const float*)d_in[24];
  const float* ffn_ng  = (const float*)d_in[25];
  const float* ffn_nb  = (const float*)d_in[26];
  const float* cls_w   = (const float*)d_in[27];
  const float* cls_g   = (const float*)d_in[28];
  const float* cls_b   = (const float*)d_in[29];
  const float* fcclsw  = (const float*)d_in[30];
  const float* fcclsb  = (const float*)d_in[31];
  const float* mask_w  = (const float*)d_in[32];
  const float* mask_g  = (const float*)d_in[33];
  const float* mask_b  = (const float*)d_in[34];
  const float* fcmw    = (const float*)d_in[35];
  const float* fcmb    = (const float*)d_in[36];
  float* out = (float*)d_out;

  // ---- workspace: 32.1 MB total (proven-safe bound is 33.03 MB) ----
  float* ws = (float*)d_ws;
  size_t off = 0;
  unsigned short* wt = (unsigned short*)(ws + off); off += 681984;  // 1,363,968 bf16
  float* fm      = ws + off; off += 204800;
  float* bias_fk = ws + off; off += 208;
  unsigned int* bitsbuf = (unsigned int*)(ws + off); off += 409600;
  unsigned short* whd = (unsigned short*)(ws + off); off += 174208;  // 348,416 bf16 head W
  float* partial = ws + off;   // union region: 8*32*100*256 = 6,553,600 floats
  float* ub = partial;
  size_t uo = 0;
  float* wb   = ub + uo; uo += 166400;  // 800 x 208 fused dysep weights
  float* pt   = ub + uo; uo += 204800;
  float* fbuf = ub + uo; uo += 204800;
  float* kkb  = ub + uo; uo += 204800;
  float* qkvb = ub + uo; uo += 614400;
  float* ob   = ub + uo; uo += 204800;
  float* mo   = ub + uo; uo += 204800;
  float* kk2  = ub + uo; uo += 204800;
  float* t1   = ub + uo; uo += 819200;  // 4 k-split slabs of 800x256
  float* objb = ub + uo; uo += 204800;
  float* mkb  = ub + uo; uo += 204800;
  unsigned short* ffn1b = (unsigned short*)(ub + uo); uo += 409600;  // 800x2048 bf16
  unsigned short* mkb16 = (unsigned short*)mkb;  // 800x256 bf16 view

  // Wt sub-offsets (shorts): fW rows 0..103, kW rows 104..207 (contiguous)
  const int wt_fW = 0, wt_kW = 26624, wt_ain = 53248, wt_aout = 249856;
  const int wt_w1 = 315392, wt_w2 = 839680;

  float* out_cls  = out;                       // [800][81]
  float* out_mask = out + 64800;               // [8][100][16384]
  float* out_obj  = out + 64800 + 13107200;    // [800][256]

  // ---- weight prep ----
  Prep6 p;
  const float* srcs[6] = {fW, kW, aw_in, aw_out, w1, w2};
  int Ks[6]    = {256, 256, 256, 256, 256, 2048};
  int Ns[6]    = {103, 103, 768, 256, 2048, 256};
  int doffs[6] = {wt_fW, wt_kW, wt_ain, wt_aout, wt_w1, wt_w2};
  int tb = 0;
  for (int i = 0; i < 6; ++i) {
    p.s[i] = srcs[i]; p.K[i] = Ks[i]; p.N[i] = Ns[i]; p.doff[i] = doffs[i];
    p.base[i] = tb;
    tb += ((Ks[i] + 31) / 32) * ((Ns[i] + 31) / 32);
  }
  prep_w<<<tb, 256, 0, stream>>>(p, wt);
  prep_bias<<<1, 256, 0, stream>>>(fb_, kb_, bias_fk);
  Cast4 cc;
  const float* csrc[4] = {cls_w, fcclsw, mask_w, fcmw};
  int cn[4] = {65536, 20736, 196608, 65536};
  int cdoff[4] = {0, 65536, 86272, 282880};
  int cb = 0;
  for (int i = 0; i < 4; ++i) {
    cc.s[i] = csrc[i]; cc.n[i] = cn[i]; cc.doff[i] = cdoff[i];
    cc.base[i] = cb;
    cb += (cn[i] + 1023) / 1024;
  }
  cast_w<<<cb, 256, 0, stream>>>(cc, whd);
  pack_bits<<<12800, 256, 0, stream>>>(maskp, bitsbuf);

  // f_masked = hard(mask) @ feat^T
  phaseA<<<dim3(32, 4, 8), 256, 0, stream>>>(bitsbuf, feat, partial);
  reduceA<<<800, 256, 0, stream>>>(partial, fm);
  // fused dysep weight GEMM: [fW | kW] in one pass (N=208)
  gemm_mf<0, 0><<<dim3(13, 4, 1), 256, 0, stream>>>(prop, wt + wt_fW, bias_fk, wb, 800, 256, 208, 208, 0, 256);
  // dysep 1
  pointdw<<<dim3(16, 8), 256, 0, stream>>>(fm, wb, pt);
  ln2_kernel<<<200, 256, 0, stream>>>(pt, fm, fng, fnb, f_ng, f_nb, fbuf);
  // dysep 2
  pointdw<<<dim3(16, 8), 256, 0, stream>>>(fbuf, wb + 104, pt);
  ln2_kernel<<<200, 256, 0, stream>>>(pt, fbuf, kng, knb, k_ng, k_nb, kkb);
  // MHA
  gemm_mf<0, 0><<<dim3(13, 12, 1), 256, 0, stream>>>(kkb, wt + wt_ain, ab_in, qkvb, 800, 256, 768, 768, 0, 256);
  attn_kernel<<<dim3(32, 8), 256, 0, stream>>>(qkvb, ob);
  gemm_mf<0, 0><<<dim3(13, 4, 1), 256, 0, stream>>>(ob, wt + wt_aout, ab_out, mo, 800, 256, 256, 256, 0, 256);
  ln_kernel<<<200, 256, 0, stream>>>(mo, kkb, s_ng, s_nb, kk2, 0, nullptr);
  // FFN: ffn1 full-K; ffn2 k-split x4 into slabs, reduced in ln_ffn2
  gemm_mf<0, 1><<<dim3(13, 32, 1), 256, 0, stream>>>(kk2, wt + wt_w1, b1, ffn1b, 800, 256, 2048, 2048, 1, 256);
  gemm_mf<1, 0><<<dim3(13, 4, 4), 256, 0, stream>>>(ffn1b, wt + wt_w2, nullptr, t1, 800, 2048, 256, 256, 0, 512);
  ln_ffn2<<<200, 256, 0, stream>>>(t1, b2, kk2, ffn_ng, ffn_nb, objb, out_obj);
  // fused cls + mask head
  head_fused<<<800, 256, 0, stream>>>(objb, whd, cls_g, cls_b, fcclsb,
                                      mask_g, mask_b, fcmb, out_cls, mkb16);
  // new_mask_preds = mk @ feat
  phaseE<<<dim3(128, 8), 256, 0, stream>>>(mkb16, feat, out_mask);
}